// Round 3
// baseline (2307.232 us; speedup 1.0000x reference)
//
#include <hip/hip_runtime.h>
#include <hip/hip_bf16.h>
#include <math.h>

typedef __hip_bfloat16 bf16;

#define L_SEQ 256
#define NB 4
#define EMB 768
#define DPOS 64
#define NH 12
#define DFF 3072
#define HD 64

// Load element i of an EXTERNAL tensor whose dtype is runtime-determined:
// f32 != 0 -> fp32, else bf16.
__device__ __forceinline__ float ldE(const void* p, size_t i, int f32) {
    return f32 ? ((const float*)p)[i]
               : __bfloat162float(((const bf16*)p)[i]);
}

// Detect input dtype (see R1 notes): fp32 read as bf16 halves -> ~24% huge
// exponents; genuine bf16 N(0,1) -> none.
__global__ void detect_kernel(const void* __restrict__ src, int* __restrict__ flagp) {
    __shared__ int cnt[256];
    int t = threadIdx.x;
    unsigned w = ((const unsigned*)src)[t];
    unsigned e = ((w & 0xFFFFu) >> 7) & 0xFFu;
    cnt[t] = (e >= 0xC3u) ? 1 : 0;
    __syncthreads();
    for (int off = 128; off; off >>= 1) {
        if (t < off) cnt[t] += cnt[t + off];
        __syncthreads();
    }
    if (t == 0) *flagp = (cnt[0] > 8) ? 1 : 0;
}

// C[M,OUT] = act( (A[M,K] @ W[OUT,K]^T + bias) * scale + residual )
// AMODE: 0 A internal fp32, 1 A external (flag dtype), 2 A internal bf16
// ACT: 0 none, 1 exact GELU. RES: 0 none, 1 fp32 residF, 2 external residE
// OUTB: 0 fp32 out, 1 bf16 out. OUTT: 1 -> write transposed kt[n][o][i] (M=1024 rows = i*4+n)
template <int AMODE, int ACT, int RES, int OUTB, int OUTT = 0>
__global__ void gemm_wt(const void* __restrict__ A, const void* __restrict__ W,
                        const void* __restrict__ bias,
                        const float* __restrict__ residF, const void* __restrict__ residE,
                        void* __restrict__ C, int M, int K, int OUT, float scale,
                        const int* __restrict__ flagp) {
    const int f32 = *flagp;
    __shared__ float As[32][33];
    __shared__ float Ws[32][33];
    int tx = threadIdx.x, ty = threadIdx.y;
    int tid = ty * 16 + tx;
    int bx = blockIdx.x, by = blockIdx.y;
    float acc00 = 0.f, acc01 = 0.f, acc10 = 0.f, acc11 = 0.f;
    for (int k0 = 0; k0 < K; k0 += 32) {
        #pragma unroll
        for (int it = 0; it < 4; ++it) {
            int l = tid + 256 * it;
            int r = l >> 5, c = l & 31;
            size_t ai = (size_t)(by * 32 + r) * K + k0 + c;
            if (AMODE == 0)      As[r][c] = ((const float*)A)[ai];
            else if (AMODE == 2) As[r][c] = __bfloat162float(((const bf16*)A)[ai]);
            else                 As[r][c] = ldE(A, ai, f32);
            Ws[r][c] = ldE(W, (size_t)(bx * 32 + r) * K + k0 + c, f32);
        }
        __syncthreads();
        #pragma unroll
        for (int kk = 0; kk < 32; ++kk) {
            float a0 = As[ty][kk], a1 = As[ty + 16][kk];
            float b0 = Ws[tx][kk], b1 = Ws[tx + 16][kk];
            acc00 += a0 * b0; acc01 += a0 * b1;
            acc10 += a1 * b0; acc11 += a1 * b1;
        }
        __syncthreads();
    }
    float accs[2][2] = {{acc00, acc01}, {acc10, acc11}};
    #pragma unroll
    for (int i = 0; i < 2; ++i)
        #pragma unroll
        for (int j = 0; j < 2; ++j) {
            int r = by * 32 + ty + i * 16;
            int o = bx * 32 + tx + j * 16;
            float v = (accs[i][j] + ldE(bias, o, f32)) * scale;
            size_t ci;
            if (OUTT) ci = ((size_t)((r & 3) * OUT + o)) * L_SEQ + (r >> 2);
            else      ci = (size_t)r * OUT + o;
            if (RES == 1) v += residF[ci];
            if (RES == 2) v += ldE(residE, ci, f32);
            if (ACT == 1) v = 0.5f * v * (1.0f + erff(v * 0.70710678118654752f));
            if (OUTB) ((bf16*)C)[ci] = __float2bfloat16(v);
            else      ((float*)C)[ci] = v;
        }
}

// Fused qp + scores + softmax + ctx. One block per (n,i), 256 threads.
// All 12 heads per block -> pos read exactly once.
__global__ __launch_bounds__(256, 4) void attn_kernel(
        const float* __restrict__ qbuf, const float* __restrict__ kt,
        const float* __restrict__ vbuf, const void* __restrict__ pos,
        const void* __restrict__ p_w, const void* __restrict__ p_b,
        float* __restrict__ ctx, const int* __restrict__ flagp) {
    const int f32 = *flagp;
    int blk = blockIdx.x;                 // n*L + i
    int i = blk & (L_SEQ - 1);
    int n = blk >> 8;
    int tid = threadIdx.x;
    int w = tid >> 6, l = tid & 63, j = tid;
    __shared__ float qs_l[768];
    __shared__ float qps_l[768];
    __shared__ float pb_l[768];
    __shared__ float qpb_l[12];
    __shared__ float prob[256][13];       // padded: conflict-free write (stride 13) & read
    __shared__ float wred[12][8];

    for (int e = tid; e < 768; e += 256) {
        qs_l[e] = qbuf[(size_t)(i * NB + n) * EMB + e];
        pb_l[e] = ldE(p_b, e, f32);
    }
    __syncthreads();

    // qps[h*64+c] = sum_d qs[h*64+d] * p_w[(h*64+d)*64 + c]
    for (int e = tid; e < 768; e += 256) {
        int h64 = e & ~63, c = e & 63;
        float acc = 0.f;
        #pragma unroll 16
        for (int d = 0; d < 64; ++d)
            acc += qs_l[h64 + d] * ldE(p_w, (size_t)(h64 + d) * DPOS + c, f32);
        qps_l[e] = acc;
    }
    if (tid < 12) {
        float acc = 0.f;
        #pragma unroll 16
        for (int d = 0; d < 64; ++d) acc += qs_l[tid * 64 + d] * pb_l[tid * 64 + d];
        qpb_l[tid] = acc;
    }

    // pos row (n,i,j,:) -> registers, vectorized
    float pr[64];
    size_t pbase = ((size_t)(n * L_SEQ + i) * L_SEQ + j) * DPOS;
    if (f32) {
        const float4* pp = (const float4*)((const float*)pos + pbase);
        #pragma unroll
        for (int t = 0; t < 16; ++t) {
            float4 v4 = pp[t];
            pr[4 * t] = v4.x; pr[4 * t + 1] = v4.y;
            pr[4 * t + 2] = v4.z; pr[4 * t + 3] = v4.w;
        }
    } else {
        const uint4* pp = (const uint4*)((const unsigned short*)pos + pbase);
        #pragma unroll
        for (int t = 0; t < 8; ++t) {
            uint4 wv = pp[t];
            unsigned a0 = wv.x, a1 = wv.y, a2 = wv.z, a3 = wv.w;
            pr[8 * t + 0] = __uint_as_float(a0 << 16);
            pr[8 * t + 1] = __uint_as_float(a0 & 0xFFFF0000u);
            pr[8 * t + 2] = __uint_as_float(a1 << 16);
            pr[8 * t + 3] = __uint_as_float(a1 & 0xFFFF0000u);
            pr[8 * t + 4] = __uint_as_float(a2 << 16);
            pr[8 * t + 5] = __uint_as_float(a2 & 0xFFFF0000u);
            pr[8 * t + 6] = __uint_as_float(a3 << 16);
            pr[8 * t + 7] = __uint_as_float(a3 & 0xFFFF0000u);
        }
    }
    __syncthreads();

    // scores for all 12 heads; k reads lane-coalesced via kt[n][e][j]
    float s[12];
    #pragma unroll
    for (int h = 0; h < 12; ++h) {
        float acc = qpb_l[h];
        const float* ktp = kt + ((size_t)n * EMB + h * HD) * L_SEQ + j;
        #pragma unroll
        for (int d4 = 0; d4 < 16; ++d4) {
            float4 q4 = *(const float4*)&qs_l[h * HD + d4 * 4];
            acc += q4.x * ktp[(d4 * 4 + 0) * L_SEQ];
            acc += q4.y * ktp[(d4 * 4 + 1) * L_SEQ];
            acc += q4.z * ktp[(d4 * 4 + 2) * L_SEQ];
            acc += q4.w * ktp[(d4 * 4 + 3) * L_SEQ];
        }
        #pragma unroll
        for (int c4 = 0; c4 < 16; ++c4) {
            float4 p4 = *(const float4*)&qps_l[h * HD + c4 * 4];
            acc += p4.x * pr[c4 * 4] + p4.y * pr[c4 * 4 + 1]
                 + p4.z * pr[c4 * 4 + 2] + p4.w * pr[c4 * 4 + 3];
        }
        s[h] = acc;
    }

    // softmax (wave shuffle + cross-wave LDS)
    #pragma unroll
    for (int h = 0; h < 12; ++h) {
        float m = s[h];
        #pragma unroll
        for (int off = 32; off; off >>= 1) m = fmaxf(m, __shfl_xor(m, off));
        if (l == 0) wred[h][w] = m;
    }
    __syncthreads();
    float p[12];
    #pragma unroll
    for (int h = 0; h < 12; ++h) {
        float m = fmaxf(fmaxf(wred[h][0], wred[h][1]), fmaxf(wred[h][2], wred[h][3]));
        p[h] = __expf(s[h] - m);
        float t = p[h];
        #pragma unroll
        for (int off = 32; off; off >>= 1) t += __shfl_xor(t, off);
        if (l == 0) wred[h][4 + w] = t;
    }
    __syncthreads();
    #pragma unroll
    for (int h = 0; h < 12; ++h) {
        float sm = wred[h][4] + wred[h][5] + wred[h][6] + wred[h][7];
        prob[j][h] = p[h] / sm;
    }
    __syncthreads();

    // ctx: 192 threads, each owns (h, d4): float4 column accumulated over all j
    if (tid < 192) {
        int h = tid >> 4, d4 = tid & 15;
        float ax = 0.f, ay = 0.f, az = 0.f, aw = 0.f;
        const float* vp = vbuf + (size_t)n * EMB + h * HD + d4 * 4;
        #pragma unroll 4
        for (int jj = 0; jj < L_SEQ; ++jj) {
            float pv = prob[jj][h];
            float4 v4 = *(const float4*)(vp + (size_t)jj * NB * EMB);
            ax += pv * v4.x; ay += pv * v4.y; az += pv * v4.z; aw += pv * v4.w;
        }
        float4 o4 = {ax, ay, az, aw};
        *(float4*)(ctx + (size_t)(i * NB + n) * EMB + h * HD + d4 * 4) = o4;
    }
}

// LayerNorm over rows of 768. FINAL: 1 -> write d_out with runtime dtype.
template <int FINAL>
__global__ void ln_kernel(const float* __restrict__ X, const void* __restrict__ g,
                          const void* __restrict__ b, float* __restrict__ outF,
                          void* __restrict__ outAny, const int* __restrict__ flagp) {
    const int f32 = *flagp;
    int r = blockIdx.x;
    int t = threadIdx.x;
    __shared__ float red[256];
    float x0 = X[(size_t)r * EMB + t];
    float x1 = X[(size_t)r * EMB + t + 256];
    float x2 = X[(size_t)r * EMB + t + 512];
    red[t] = x0 + x1 + x2;
    __syncthreads();
    for (int off = 128; off; off >>= 1) {
        if (t < off) red[t] += red[t + off];
        __syncthreads();
    }
    float mean = red[0] * (1.0f / EMB);
    __syncthreads();
    float d0 = x0 - mean, d1 = x1 - mean, d2 = x2 - mean;
    red[t] = d0 * d0 + d1 * d1 + d2 * d2;
    __syncthreads();
    for (int off = 128; off; off >>= 1) {
        if (t < off) red[t] += red[t + off];
        __syncthreads();
    }
    float rstd = rsqrtf(red[0] * (1.0f / EMB) + 1e-5f);
    float vs[3] = {d0, d1, d2};
    #pragma unroll
    for (int pp = 0; pp < 3; ++pp) {
        int e = t + pp * 256;
        float v = vs[pp] * rstd * ldE(g, e, f32) + ldE(b, e, f32);
        size_t oi = (size_t)r * EMB + e;
        if (FINAL) {
            if (f32) ((float*)outAny)[oi] = v;
            else     ((bf16*)outAny)[oi] = __float2bfloat16(v);
        } else {
            outF[oi] = v;
        }
    }
}

extern "C" void kernel_launch(void* const* d_in, const int* in_sizes, int n_in,
                              void* d_out, int out_size, void* d_ws, size_t ws_size,
                              hipStream_t stream) {
    const void* src    = d_in[0];
    const void* pos    = d_in[1];
    const void* q_w    = d_in[2];
    const void* q_b    = d_in[3];
    const void* k_w    = d_in[4];
    const void* k_b    = d_in[5];
    const void* v_w    = d_in[6];
    const void* v_b    = d_in[7];
    const void* p_w    = d_in[8];
    const void* p_b    = d_in[9];
    const void* out_w  = d_in[10];
    const void* out_b  = d_in[11];
    const void* lin1_w = d_in[12];
    const void* lin1_b = d_in[13];
    const void* lin2_w = d_in[14];
    const void* lin2_b = d_in[15];
    const void* n1_g   = d_in[16];
    const void* n1_b   = d_in[17];
    const void* n2_g   = d_in[18];
    const void* n2_b   = d_in[19];

    const int M = L_SEQ * NB;            // 1024
    float* f = (float*)d_ws;
    // Overlays (float offsets):
    //   [0]        qbuf (dead after attn)  -> y (out-proj) -> y2 (lin2 out)
    //   [786432]   kt   (dead after attn)  -> x1 (ln1 out)
    //   [1572864]  vbuf (dead after attn) + [2359296] ctx (dead after out-proj)
    //              -> ff (bf16, 3145728 elems = 1572864 float slots) spans both
    float* qbuf = f;
    float* kt   = f + 786432;
    float* vbuf = f + 1572864;
    float* ctx  = f + 2359296;
    bf16*  ff   = (bf16*)(f + 1572864);
    float* y    = qbuf;
    float* x1   = kt;
    float* y2   = qbuf;
    int*   flagp = (int*)(f + 3145728);  // ~12.6 MB total

    dim3 thr(16, 16);
    const float scaling = 0.125f;        // 64^-0.5

    detect_kernel<<<1, 256, 0, stream>>>(src, flagp);

    // Q/K/V projections (K written transposed: kt[n][e][i])
    gemm_wt<1, 0, 0, 0><<<dim3(EMB / 32, M / 32), thr, 0, stream>>>(
        src, q_w, q_b, nullptr, nullptr, qbuf, M, EMB, EMB, scaling, flagp);
    gemm_wt<1, 0, 0, 0, 1><<<dim3(EMB / 32, M / 32), thr, 0, stream>>>(
        src, k_w, k_b, nullptr, nullptr, kt, M, EMB, EMB, 1.0f, flagp);
    gemm_wt<1, 0, 0, 0><<<dim3(EMB / 32, M / 32), thr, 0, stream>>>(
        src, v_w, v_b, nullptr, nullptr, vbuf, M, EMB, EMB, 1.0f, flagp);

    // fused qp + scores + softmax + ctx
    attn_kernel<<<NB * L_SEQ, 256, 0, stream>>>(qbuf, kt, vbuf, pos, p_w, p_b,
                                                ctx, flagp);

    // out projection + residual(src) -> y ; LN1 -> x1
    gemm_wt<0, 0, 2, 0><<<dim3(EMB / 32, M / 32), thr, 0, stream>>>(
        ctx, out_w, out_b, nullptr, src, y, M, EMB, EMB, 1.0f, flagp);
    ln_kernel<0><<<M, 256, 0, stream>>>(y, n1_g, n1_b, x1, nullptr, flagp);

    // FF: lin1 + GELU -> ff (bf16), lin2 + residual(x1) -> y2
    gemm_wt<0, 1, 0, 1><<<dim3(DFF / 32, M / 32), thr, 0, stream>>>(
        x1, lin1_w, lin1_b, nullptr, nullptr, ff, M, EMB, DFF, 1.0f, flagp);
    gemm_wt<2, 0, 1, 0><<<dim3(EMB / 32, M / 32), thr, 0, stream>>>(
        ff, lin2_w, lin2_b, x1, nullptr, y2, M, DFF, EMB, 1.0f, flagp);
    ln_kernel<1><<<M, 256, 0, stream>>>(y2, n2_g, n2_b, nullptr, d_out, flagp);
}

// Round 4
// 539.754 us; speedup vs baseline: 4.2746x; 4.2746x over previous
//
#include <hip/hip_runtime.h>
#include <hip/hip_bf16.h>
#include <math.h>

typedef __hip_bfloat16 bf16;
typedef unsigned short u16;
typedef __attribute__((ext_vector_type(8))) short bf16x8;
typedef __attribute__((ext_vector_type(4))) float f32x4;

#define L_SEQ 256
#define NB 4
#define EMB 768
#define NH 12
#define DFF 3072
#define HD 64

__device__ __forceinline__ float ldE(const void* p, size_t i, int f32) {
    return f32 ? ((const float*)p)[i] : __bfloat162float(((const bf16*)p)[i]);
}
__device__ __forceinline__ float b2f(u16 v) { return __uint_as_float(((unsigned)v) << 16); }
__device__ __forceinline__ u16 f2b(float v) {
    bf16 h = __float2bfloat16(v);
    return *(u16*)&h;
}

// Runtime input dtype detect: fp32 words read as bf16 halves -> huge exponents.
__global__ void detect_kernel(const void* __restrict__ src, int* __restrict__ flagp) {
    __shared__ int cnt[256];
    int t = threadIdx.x;
    unsigned w = ((const unsigned*)src)[t];
    unsigned e = ((w & 0xFFFFu) >> 7) & 0xFFu;
    cnt[t] = (e >= 0xC3u) ? 1 : 0;
    __syncthreads();
    for (int off = 128; off; off >>= 1) {
        if (t < off) cnt[t] += cnt[t + off];
        __syncthreads();
    }
    if (t == 0) *flagp = (cnt[0] > 8) ? 1 : 0;
}

// Convert one tensor to bf16 (or copy if already bf16). n multiple of 8.
__global__ void pack_w(u16* __restrict__ dst, const void* __restrict__ src, int n,
                       const int* __restrict__ flagp) {
    const int f32 = *flagp;
    int idx = (blockIdx.x * 256 + threadIdx.x) * 8;
    if (idx >= n) return;
    if (f32) {
        const float* s = (const float*)src + idx;
        u16 tmp[8];
        #pragma unroll
        for (int t = 0; t < 8; ++t) tmp[t] = f2b(s[t]);
        *(uint4*)(dst + idx) = *(uint4*)tmp;
    } else {
        *(uint4*)(dst + idx) = *(const uint4*)((const u16*)src + idx);
    }
}

// Pack q_w|k_w|v_w stacked into wqkv [2304][768] bf16.
__global__ void pack_qkvw(u16* __restrict__ dst, const void* __restrict__ qw,
                          const void* __restrict__ kw, const void* __restrict__ vw,
                          const int* __restrict__ flagp) {
    const int f32 = *flagp;
    int idx = (blockIdx.x * 256 + threadIdx.x) * 8;   // < 2304*768
    int r = idx / EMB;
    const void* s;
    int off;
    if (r < EMB)            { s = qw; off = idx; }
    else if (r < 2 * EMB)   { s = kw; off = idx - EMB * EMB; }
    else                    { s = vw; off = idx - 2 * EMB * EMB; }
    if (f32) {
        const float* sf = (const float*)s + off;
        u16 tmp[8];
        #pragma unroll
        for (int t = 0; t < 8; ++t) tmp[t] = f2b(sf[t]);
        *(uint4*)(dst + idx) = *(uint4*)tmp;
    } else {
        *(uint4*)(dst + idx) = *(const uint4*)((const u16*)s + off);
    }
}

// All biases -> fp32: [0,2304)=q|k|v, [2304,3072)=out, [3072,6144)=lin1, [6144,6912)=lin2
__global__ void pack_bias(float* __restrict__ dst, const void* qb, const void* kb,
                          const void* vb, const void* ob, const void* l1,
                          const void* l2, const int* __restrict__ flagp) {
    const int f32 = *flagp;
    int o = blockIdx.x * 256 + threadIdx.x;
    if (o >= 6912) return;
    float v;
    if (o < 768)       v = ldE(qb, o, f32);
    else if (o < 1536) v = ldE(kb, o - 768, f32);
    else if (o < 2304) v = ldE(vb, o - 1536, f32);
    else if (o < 3072) v = ldE(ob, o - 2304, f32);
    else if (o < 6144) v = ldE(l1, o - 3072, f32);
    else               v = ldE(l2, o - 6144, f32);
    dst[o] = v;
}

// MFMA bf16 GEMM: C[M,N] = A[M,K] @ W[N,K]^T (+bias, epilogue per MODE).
// 128x128 tile, 4 waves, each 64x64 via 4x4 16x16x32 frags. M=1024 always.
// MODE 0: qkv split -> outB0/1/2 bf16 (q scaled 0.125), stride EMB
// MODE 1: + residE (runtime dtype) -> outF fp32, stride EMB
// MODE 2: GELU -> outB0 bf16, stride DFF
// MODE 3: + residF fp32 -> outF fp32, stride EMB
template <int MODE>
__global__ __launch_bounds__(256) void mfma_gemm(
        const u16* __restrict__ A, const u16* __restrict__ W,
        const float* __restrict__ biasf,
        u16* __restrict__ outB0, u16* __restrict__ outB1, u16* __restrict__ outB2,
        float* __restrict__ outF, const void* __restrict__ residE,
        const float* __restrict__ residF, int K, const int* __restrict__ flagp) {
    __shared__ u16 As[128][40];   // pad 32->40 (80B rows: 2-way bank alias, free)
    __shared__ u16 Ws[128][40];
    int tid = threadIdx.x;
    int wave = tid >> 6, lane = tid & 63;
    int quad = lane >> 4, col = lane & 15;
    int m0 = blockIdx.y * 128, n0 = blockIdx.x * 128;
    int wm = (wave >> 1) * 64, wn = (wave & 1) * 64;
    f32x4 acc[4][4];
    #pragma unroll
    for (int a = 0; a < 4; ++a)
        #pragma unroll
        for (int b = 0; b < 4; ++b) acc[a][b] = (f32x4){0.f, 0.f, 0.f, 0.f};
    for (int k0 = 0; k0 < K; k0 += 32) {
        #pragma unroll
        for (int it = 0; it < 2; ++it) {
            int l = tid + it * 256;
            int r = l >> 2, c4 = (l & 3) * 8;
            *(uint4*)&As[r][c4] = *(const uint4*)&A[(size_t)(m0 + r) * K + k0 + c4];
            *(uint4*)&Ws[r][c4] = *(const uint4*)&W[(size_t)(n0 + r) * K + k0 + c4];
        }
        __syncthreads();
        bf16x8 af[4], bfr[4];
        #pragma unroll
        for (int mi = 0; mi < 4; ++mi)
            af[mi] = __builtin_bit_cast(bf16x8, *(const uint4*)&As[wm + mi * 16 + col][quad * 8]);
        #pragma unroll
        for (int ni = 0; ni < 4; ++ni)
            bfr[ni] = __builtin_bit_cast(bf16x8, *(const uint4*)&Ws[wn + ni * 16 + col][quad * 8]);
        #pragma unroll
        for (int mi = 0; mi < 4; ++mi)
            #pragma unroll
            for (int ni = 0; ni < 4; ++ni)
                acc[mi][ni] = __builtin_amdgcn_mfma_f32_16x16x32_bf16(
                    af[mi], bfr[ni], acc[mi][ni], 0, 0, 0);
        __syncthreads();
    }
    const int f32 = *flagp;
    #pragma unroll
    for (int mi = 0; mi < 4; ++mi)
        #pragma unroll
        for (int ni = 0; ni < 4; ++ni)
            #pragma unroll
            for (int reg = 0; reg < 4; ++reg) {
                int rr = m0 + wm + mi * 16 + quad * 4 + reg;
                int cc = n0 + wn + ni * 16 + col;
                float v = acc[mi][ni][reg] + biasf[cc];
                if (MODE == 0) {
                    if (cc < EMB) {
                        outB0[(size_t)rr * EMB + cc] = f2b(v * 0.125f);
                    } else if (cc < 2 * EMB) {
                        outB1[(size_t)rr * EMB + cc - EMB] = f2b(v);
                    } else {
                        outB2[(size_t)rr * EMB + cc - 2 * EMB] = f2b(v);
                    }
                } else if (MODE == 1) {
                    v += ldE(residE, (size_t)rr * EMB + cc, f32);
                    outF[(size_t)rr * EMB + cc] = v;
                } else if (MODE == 2) {
                    v = 0.5f * v * (1.0f + erff(v * 0.70710678118654752f));
                    outB0[(size_t)rr * DFF + cc] = f2b(v);
                } else {
                    v += residF[(size_t)rr * EMB + cc];
                    outF[(size_t)rr * EMB + cc] = v;
                }
            }
}

// qp[n,h,i,c] = sum_d q[i,n,h,d] p_w[h*64+d, c]; qpb = q . p_b   (q pre-scaled)
__global__ void qp_kernel(const u16* __restrict__ qb, const void* __restrict__ p_w,
                          const void* __restrict__ p_b, float* __restrict__ qp,
                          float* __restrict__ qpb, const int* __restrict__ flagp) {
    const int f32 = *flagp;
    int blk = blockIdx.x;                // (n*NH+h)*L + i
    int i = blk & 255;
    int h = (blk >> 8) % NH;
    int n = blk / (256 * NH);
    int t = threadIdx.x;                 // 0..63
    __shared__ float qs[64];
    qs[t] = b2f(qb[(size_t)(i * NB + n) * EMB + h * HD + t]);
    __syncthreads();
    float acc = 0.f;
    #pragma unroll 16
    for (int d = 0; d < 64; ++d)
        acc += qs[d] * ldE(p_w, (size_t)(h * HD + d) * HD + t, f32);
    qp[(size_t)blk * 64 + t] = acc;
    float v = qs[t] * ldE(p_b, h * HD + t, f32);
    #pragma unroll
    for (int off = 32; off; off >>= 1) v += __shfl_down(v, off);
    if (t == 0) qpb[blk] = v;
}

// S[n,h,i,j] = sum_c pos[n,i,j,c]*qp[n,h,i,c] + qpb[n,h,i]. Block per (n,i):
// pos read exactly once, 12 running sums per thread (no big register arrays).
__global__ __launch_bounds__(256) void s2_kernel(
        const float* __restrict__ qp, const float* __restrict__ qpb,
        const void* __restrict__ pos, float* __restrict__ S,
        const int* __restrict__ flagp) {
    const int f32 = *flagp;
    int blk = blockIdx.x;                // n*L + i
    int i = blk & 255, n = blk >> 8;
    int j = threadIdx.x;
    __shared__ float qps[768];
    __shared__ float qpbl[12];
    for (int e = j; e < 768; e += 256) {
        int h = e >> 6, c = e & 63;
        qps[e] = qp[((size_t)((n * NH + h) * L_SEQ + i)) * 64 + c];
    }
    if (j < 12) qpbl[j] = qpb[(size_t)(n * NH + j) * L_SEQ + i];
    __syncthreads();
    float s2[12];
    #pragma unroll
    for (int h = 0; h < 12; ++h) s2[h] = 0.f;
    size_t pbase = ((size_t)(n * L_SEQ + i) * L_SEQ + j) * HD;
    for (int c0 = 0; c0 < 64; c0 += 8) {
        float pr[8];
        if (f32) {
            float4 a = *(const float4*)((const float*)pos + pbase + c0);
            float4 b = *(const float4*)((const float*)pos + pbase + c0 + 4);
            pr[0] = a.x; pr[1] = a.y; pr[2] = a.z; pr[3] = a.w;
            pr[4] = b.x; pr[5] = b.y; pr[6] = b.z; pr[7] = b.w;
        } else {
            uint4 u = *(const uint4*)((const u16*)pos + pbase + c0);
            pr[0] = __uint_as_float(u.x << 16); pr[1] = __uint_as_float(u.x & 0xFFFF0000u);
            pr[2] = __uint_as_float(u.y << 16); pr[3] = __uint_as_float(u.y & 0xFFFF0000u);
            pr[4] = __uint_as_float(u.z << 16); pr[5] = __uint_as_float(u.z & 0xFFFF0000u);
            pr[6] = __uint_as_float(u.w << 16); pr[7] = __uint_as_float(u.w & 0xFFFF0000u);
        }
        #pragma unroll
        for (int h = 0; h < 12; ++h) {
            const float* qq = &qps[h * 64 + c0];
            #pragma unroll
            for (int t = 0; t < 8; ++t) s2[h] += pr[t] * qq[t];
        }
    }
    #pragma unroll
    for (int h = 0; h < 12; ++h)
        S[(size_t)((n * NH + h) * L_SEQ + i) * L_SEQ + j] = s2[h] + qpbl[h];
}

// scores = q.k + S, softmax, ctx = P@V. Block per (n,h,i), 256 threads.
__global__ __launch_bounds__(256) void attn2_kernel(
        const u16* __restrict__ qb, const u16* __restrict__ kb,
        const u16* __restrict__ vb, const float* __restrict__ S,
        u16* __restrict__ ctxb) {
    int blk = blockIdx.x;                // (n*NH+h)*L + i
    int i = blk & 255;
    int h = (blk >> 8) % NH;
    int n = blk / (256 * NH);
    int j = threadIdx.x;
    __shared__ float qs[64];
    __shared__ float red[256];
    __shared__ float prob[256];
    __shared__ float part[16][68];
    if (j < 64) qs[j] = b2f(qb[(size_t)(i * NB + n) * EMB + h * HD + j]);
    __syncthreads();
    const u16* krow = kb + (size_t)(j * NB + n) * EMB + h * HD;
    float s = S[(size_t)((n * NH + h) * L_SEQ + i) * L_SEQ + j];
    #pragma unroll
    for (int q8 = 0; q8 < 8; ++q8) {
        uint4 u = *(const uint4*)(krow + q8 * 8);
        const float* qq = &qs[q8 * 8];
        s += qq[0] * __uint_as_float(u.x << 16);
        s += qq[1] * __uint_as_float(u.x & 0xFFFF0000u);
        s += qq[2] * __uint_as_float(u.y << 16);
        s += qq[3] * __uint_as_float(u.y & 0xFFFF0000u);
        s += qq[4] * __uint_as_float(u.z << 16);
        s += qq[5] * __uint_as_float(u.z & 0xFFFF0000u);
        s += qq[6] * __uint_as_float(u.w << 16);
        s += qq[7] * __uint_as_float(u.w & 0xFFFF0000u);
    }
    red[j] = s;
    __syncthreads();
    for (int off = 128; off; off >>= 1) {
        if (j < off) red[j] = fmaxf(red[j], red[j + off]);
        __syncthreads();
    }
    float mx = red[0];
    __syncthreads();
    float e = __expf(s - mx);
    red[j] = e;
    __syncthreads();
    for (int off = 128; off; off >>= 1) {
        if (j < off) red[j] += red[j + off];
        __syncthreads();
    }
    prob[j] = e * (1.0f / red[0]);
    __syncthreads();
    // ctx: thread (g=j>>4 over 16 key-chunks, d4=j&15 over 4 head dims)
    int g = j >> 4, d4 = j & 15;
    float ax = 0.f, ay = 0.f, az = 0.f, aw = 0.f;
    #pragma unroll 4
    for (int t = 0; t < 16; ++t) {
        int jj = g * 16 + t;
        float pv = prob[jj];
        uint2 u = *(const uint2*)(vb + (size_t)(jj * NB + n) * EMB + h * HD + d4 * 4);
        ax += pv * __uint_as_float(u.x << 16);
        ay += pv * __uint_as_float(u.x & 0xFFFF0000u);
        az += pv * __uint_as_float(u.y << 16);
        aw += pv * __uint_as_float(u.y & 0xFFFF0000u);
    }
    part[g][d4 * 4 + 0] = ax;
    part[g][d4 * 4 + 1] = ay;
    part[g][d4 * 4 + 2] = az;
    part[g][d4 * 4 + 3] = aw;
    __syncthreads();
    if (j < 64) {
        float v = 0.f;
        #pragma unroll
        for (int g2 = 0; g2 < 16; ++g2) v += part[g2][j];
        ctxb[(size_t)(i * NB + n) * EMB + h * HD + j] = f2b(v);
    }
}

// LayerNorm rows of 768. FINAL=0: write x1f fp32 AND x1b bf16. FINAL=1: d_out runtime.
template <int FINAL>
__global__ void ln_kernel(const float* __restrict__ X, const void* __restrict__ g,
                          const void* __restrict__ b, float* __restrict__ outF,
                          u16* __restrict__ outB, void* __restrict__ outAny,
                          const int* __restrict__ flagp) {
    const int f32 = *flagp;
    int r = blockIdx.x;
    int t = threadIdx.x;
    __shared__ float red[256];
    float x0 = X[(size_t)r * EMB + t];
    float x1 = X[(size_t)r * EMB + t + 256];
    float x2 = X[(size_t)r * EMB + t + 512];
    red[t] = x0 + x1 + x2;
    __syncthreads();
    for (int off = 128; off; off >>= 1) {
        if (t < off) red[t] += red[t + off];
        __syncthreads();
    }
    float mean = red[0] * (1.0f / EMB);
    __syncthreads();
    float d0 = x0 - mean, d1 = x1 - mean, d2 = x2 - mean;
    red[t] = d0 * d0 + d1 * d1 + d2 * d2;
    __syncthreads();
    for (int off = 128; off; off >>= 1) {
        if (t < off) red[t] += red[t + off];
        __syncthreads();
    }
    float rstd = rsqrtf(red[0] * (1.0f / EMB) + 1e-5f);
    float vs[3] = {d0, d1, d2};
    #pragma unroll
    for (int p = 0; p < 3; ++p) {
        int e = t + p * 256;
        float v = vs[p] * rstd * ldE(g, e, f32) + ldE(b, e, f32);
        size_t oi = (size_t)r * EMB + e;
        if (FINAL) {
            if (f32) ((float*)outAny)[oi] = v;
            else     ((bf16*)outAny)[oi] = __float2bfloat16(v);
        } else {
            outF[oi] = v;
            outB[oi] = f2b(v);
        }
    }
}

extern "C" void kernel_launch(void* const* d_in, const int* in_sizes, int n_in,
                              void* d_out, int out_size, void* d_ws, size_t ws_size,
                              hipStream_t stream) {
    const void* src    = d_in[0];
    const void* pos    = d_in[1];
    const void* q_w    = d_in[2];
    const void* q_b    = d_in[3];
    const void* k_w    = d_in[4];
    const void* k_b    = d_in[5];
    const void* v_w    = d_in[6];
    const void* v_b    = d_in[7];
    const void* p_w    = d_in[8];
    const void* p_b    = d_in[9];
    const void* out_w  = d_in[10];
    const void* out_b  = d_in[11];
    const void* lin1_w = d_in[12];
    const void* lin1_b = d_in[13];
    const void* lin2_w = d_in[14];
    const void* lin2_b = d_in[15];
    const void* n1_g   = d_in[16];
    const void* n1_b   = d_in[17];
    const void* n2_g   = d_in[18];
    const void* n2_b   = d_in[19];

    float* f = (float*)d_ws;
    // layout in float slots (all 16-float aligned); ~37.8 MB total
    int*   flagp = (int*)f;                              // 16
    float* biasf = f + 16;                               // 6912
    u16*   xb    = (u16*)(f + 6928);                     // 786432 bf16 = 393216 f
    u16*   wqkv  = (u16*)(f + 400144);                   // 1769472 bf16 = 884736 f
    u16*   owb   = (u16*)(f + 1284880);                  // 589824 bf16 = 294912 f
    u16*   l1b   = (u16*)(f + 1579792);                  // 2359296 bf16 = 1179648 f
    u16*   l2b   = (u16*)(f + 2759440);                  // 2359296 bf16 = 1179648 f
    u16*   qbp   = (u16*)(f + 3939088);                  // 393216 f
    u16*   kbp   = (u16*)(f + 4332304);                  // 393216 f
    u16*   vbp   = (u16*)(f + 4725520);                  // 393216 f
    float* qp    = f + 5118736;                          // 786432
    float* qpb   = f + 5905168;                          // 12288
    float* S     = f + 5917456;                          // 3145728
    u16*   ctxb  = (u16*)(f + 9063184);                  // 393216 f  (end 9456400)
    // overlays:
    float* y   = qp;                                     // qp dead after s2
    float* x1f = (float*)qbp;                            // qb+kb dead after attn2
    u16*   x1b = vbp;                                    // vb dead after attn2
    u16*   ffb = (u16*)S;                                // S dead after attn2 (1572864 f)
    float* y2  = S + 1572864;                            // within S region

    detect_kernel<<<1, 256, 0, stream>>>(src, flagp);

    // pack weights/activations to bf16, biases to fp32
    pack_w<<<384, 256, 0, stream>>>(xb, src, 786432, flagp);
    pack_qkvw<<<864, 256, 0, stream>>>(wqkv, q_w, k_w, v_w, flagp);
    pack_w<<<288, 256, 0, stream>>>(owb, out_w, 589824, flagp);
    pack_w<<<1152, 256, 0, stream>>>(l1b, lin1_w, 2359296, flagp);
    pack_w<<<1152, 256, 0, stream>>>(l2b, lin2_w, 2359296, flagp);
    pack_bias<<<27, 256, 0, stream>>>(biasf, q_b, k_b, v_b, out_b, lin1_b, lin2_b, flagp);

    // QKV fused GEMM (N=2304)
    mfma_gemm<0><<<dim3(18, 8), 256, 0, stream>>>(
        xb, wqkv, biasf, qbp, kbp, vbp, nullptr, nullptr, nullptr, EMB, flagp);

    // position scores
    qp_kernel<<<NB * NH * L_SEQ, 64, 0, stream>>>(qbp, p_w, p_b, qp, qpb, flagp);
    s2_kernel<<<NB * L_SEQ, 256, 0, stream>>>(qp, qpb, pos, S, flagp);

    // attention
    attn2_kernel<<<NB * NH * L_SEQ, 256, 0, stream>>>(qbp, kbp, vbp, S, ctxb);

    // out projection + residual(src) -> y fp32 ; LN1 -> x1f fp32 + x1b bf16
    mfma_gemm<1><<<dim3(6, 8), 256, 0, stream>>>(
        ctxb, owb, biasf + 2304, nullptr, nullptr, nullptr, y, src, nullptr, EMB, flagp);
    ln_kernel<0><<<1024, 256, 0, stream>>>(y, n1_g, n1_b, x1f, x1b, nullptr, flagp);

    // FF
    mfma_gemm<2><<<dim3(24, 8), 256, 0, stream>>>(
        x1b, l1b, biasf + 3072, ffb, nullptr, nullptr, nullptr, nullptr, nullptr, EMB, flagp);
    mfma_gemm<3><<<dim3(6, 8), 256, 0, stream>>>(
        ffb, l2b, biasf + 6144, nullptr, nullptr, nullptr, y2, nullptr, x1f, DFF, flagp);
    ln_kernel<1><<<1024, 256, 0, stream>>>(y2, n2_g, n2_b, nullptr, nullptr, d_out, flagp);
}

// Round 5
// 427.149 us; speedup vs baseline: 5.4015x; 1.2636x over previous
//
#include <hip/hip_runtime.h>
#include <hip/hip_bf16.h>
#include <math.h>

typedef __hip_bfloat16 bf16;
typedef unsigned short u16;
typedef __attribute__((ext_vector_type(8))) short bf16x8;
typedef __attribute__((ext_vector_type(4))) float f32x4;

#define L_SEQ 256
#define NB 4
#define EMB 768
#define NH 12
#define DFF 3072
#define HD 64

__device__ __forceinline__ float ldE(const void* p, size_t i, int f32) {
    return f32 ? ((const float*)p)[i] : __bfloat162float(((const bf16*)p)[i]);
}
__device__ __forceinline__ float b2f(u16 v) { return __uint_as_float(((unsigned)v) << 16); }
__device__ __forceinline__ u16 f2b(float v) {
    bf16 h = __float2bfloat16(v);
    return *(u16*)&h;
}

// Runtime input dtype detect: fp32 words read as bf16 halves -> huge exponents.
__global__ void detect_kernel(const void* __restrict__ src, int* __restrict__ flagp) {
    __shared__ int cnt[256];
    int t = threadIdx.x;
    unsigned w = ((const unsigned*)src)[t];
    unsigned e = ((w & 0xFFFFu) >> 7) & 0xFFu;
    cnt[t] = (e >= 0xC3u) ? 1 : 0;
    __syncthreads();
    for (int off = 128; off; off >>= 1) {
        if (t < off) cnt[t] += cnt[t + off];
        __syncthreads();
    }
    if (t == 0) *flagp = (cnt[0] > 8) ? 1 : 0;
}

__device__ __forceinline__ void cvt8(u16* dst, const void* s, size_t off, int f32) {
    if (f32) {
        const float* sf = (const float*)s + off;
        #pragma unroll
        for (int t = 0; t < 8; ++t) dst[t] = f2b(sf[t]);
    } else {
        *(uint4*)dst = *(const uint4*)((const u16*)s + off);
    }
}

// One kernel packs ALL weights/activations to bf16 and all biases to fp32.
// Work unit = 8 elems. Segments (8-elem units): xb 98304 | wqkv 221184 |
// owb 73728 | l1b 294912 | l2b 294912  (total 983040 -> 3840 blocks).
// Blocks 3840..3866 write biasf (6912 floats).
__global__ void pack_all(u16* __restrict__ xb, u16* __restrict__ wqkv,
                         u16* __restrict__ owb, u16* __restrict__ l1b,
                         u16* __restrict__ l2b, float* __restrict__ biasf,
                         const void* src, const void* qw, const void* kw, const void* vw,
                         const void* ow, const void* l1w, const void* l2w,
                         const void* qb, const void* kb, const void* vb,
                         const void* ob, const void* b1, const void* b2,
                         const int* __restrict__ flagp) {
    const int f32 = *flagp;
    int b = blockIdx.x;
    if (b >= 3840) {
        int o = (b - 3840) * 256 + threadIdx.x;
        if (o >= 6912) return;
        float v;
        if (o < 768)       v = ldE(qb, o, f32);
        else if (o < 1536) v = ldE(kb, o - 768, f32);
        else if (o < 2304) v = ldE(vb, o - 1536, f32);
        else if (o < 3072) v = ldE(ob, o - 2304, f32);
        else if (o < 6144) v = ldE(b1, o - 3072, f32);
        else               v = ldE(b2, o - 6144, f32);
        biasf[o] = v;
        return;
    }
    int gid = b * 256 + threadIdx.x;
    u16 tmp[8];
    if (gid < 98304) {
        size_t idx = (size_t)gid * 8;
        cvt8(tmp, src, idx, f32);
        *(uint4*)(xb + idx) = *(uint4*)tmp;
    } else if (gid < 319488) {
        size_t idx = (size_t)(gid - 98304) * 8;
        int r = (int)(idx / EMB);
        const void* s;
        size_t off;
        if (r < EMB)          { s = qw; off = idx; }
        else if (r < 2 * EMB) { s = kw; off = idx - (size_t)EMB * EMB; }
        else                  { s = vw; off = idx - (size_t)2 * EMB * EMB; }
        cvt8(tmp, s, off, f32);
        *(uint4*)(wqkv + idx) = *(uint4*)tmp;
    } else if (gid < 393216) {
        size_t idx = (size_t)(gid - 319488) * 8;
        cvt8(tmp, ow, idx, f32);
        *(uint4*)(owb + idx) = *(uint4*)tmp;
    } else if (gid < 688128) {
        size_t idx = (size_t)(gid - 393216) * 8;
        cvt8(tmp, l1w, idx, f32);
        *(uint4*)(l1b + idx) = *(uint4*)tmp;
    } else {
        size_t idx = (size_t)(gid - 688128) * 8;
        cvt8(tmp, l2w, idx, f32);
        *(uint4*)(l2b + idx) = *(uint4*)tmp;
    }
}

// MFMA bf16 GEMM: C[M,N] = A[M,K] @ W[N,K]^T (+bias, epilogue per MODE).
// 128x128 tile, 4 waves, each 64x64 via 4x4 16x16x32 frags. M=1024 always.
// MODE 0: qkv split -> outB0/1/2 bf16 (q scaled 0.125), stride EMB
// MODE 1: + residE (runtime dtype) -> outF fp32, stride EMB
// MODE 2: GELU -> outB0 bf16, stride DFF
// MODE 3: + residF fp32 -> outF fp32, stride EMB
template <int MODE>
__global__ __launch_bounds__(256) void mfma_gemm(
        const u16* __restrict__ A, const u16* __restrict__ W,
        const float* __restrict__ biasf,
        u16* __restrict__ outB0, u16* __restrict__ outB1, u16* __restrict__ outB2,
        float* __restrict__ outF, const void* __restrict__ residE,
        const float* __restrict__ residF, int K, const int* __restrict__ flagp) {
    __shared__ u16 As[128][40];   // pad 32->40 (80B rows: 2-way bank alias, free)
    __shared__ u16 Ws[128][40];
    int tid = threadIdx.x;
    int wave = tid >> 6, lane = tid & 63;
    int quad = lane >> 4, col = lane & 15;
    int m0 = blockIdx.y * 128, n0 = blockIdx.x * 128;
    int wm = (wave >> 1) * 64, wn = (wave & 1) * 64;
    f32x4 acc[4][4];
    #pragma unroll
    for (int a = 0; a < 4; ++a)
        #pragma unroll
        for (int b = 0; b < 4; ++b) acc[a][b] = (f32x4){0.f, 0.f, 0.f, 0.f};
    for (int k0 = 0; k0 < K; k0 += 32) {
        #pragma unroll
        for (int it = 0; it < 2; ++it) {
            int l = tid + it * 256;
            int r = l >> 2, c4 = (l & 3) * 8;
            *(uint4*)&As[r][c4] = *(const uint4*)&A[(size_t)(m0 + r) * K + k0 + c4];
            *(uint4*)&Ws[r][c4] = *(const uint4*)&W[(size_t)(n0 + r) * K + k0 + c4];
        }
        __syncthreads();
        bf16x8 af[4], bfr[4];
        #pragma unroll
        for (int mi = 0; mi < 4; ++mi)
            af[mi] = __builtin_bit_cast(bf16x8, *(const uint4*)&As[wm + mi * 16 + col][quad * 8]);
        #pragma unroll
        for (int ni = 0; ni < 4; ++ni)
            bfr[ni] = __builtin_bit_cast(bf16x8, *(const uint4*)&Ws[wn + ni * 16 + col][quad * 8]);
        #pragma unroll
        for (int mi = 0; mi < 4; ++mi)
            #pragma unroll
            for (int ni = 0; ni < 4; ++ni)
                acc[mi][ni] = __builtin_amdgcn_mfma_f32_16x16x32_bf16(
                    af[mi], bfr[ni], acc[mi][ni], 0, 0, 0);
        __syncthreads();
    }
    const int f32 = *flagp;
    #pragma unroll
    for (int mi = 0; mi < 4; ++mi)
        #pragma unroll
        for (int ni = 0; ni < 4; ++ni)
            #pragma unroll
            for (int reg = 0; reg < 4; ++reg) {
                int rr = m0 + wm + mi * 16 + quad * 4 + reg;
                int cc = n0 + wn + ni * 16 + col;
                float v = acc[mi][ni][reg] + biasf[cc];
                if (MODE == 0) {
                    if (cc < EMB) {
                        outB0[(size_t)rr * EMB + cc] = f2b(v * 0.125f);
                    } else if (cc < 2 * EMB) {
                        outB1[(size_t)rr * EMB + cc - EMB] = f2b(v);
                    } else {
                        outB2[(size_t)rr * EMB + cc - 2 * EMB] = f2b(v);
                    }
                } else if (MODE == 1) {
                    v += ldE(residE, (size_t)rr * EMB + cc, f32);
                    outF[(size_t)rr * EMB + cc] = v;
                } else if (MODE == 2) {
                    v = 0.5f * v * (1.0f + erff(v * 0.70710678118654752f));
                    outB0[(size_t)rr * DFF + cc] = f2b(v);
                } else {
                    v += residF[(size_t)rr * EMB + cc];
                    outF[(size_t)rr * EMB + cc] = v;
                }
            }
}

// qp_b[n,i,h,c] (bf16, h padded to 16) = sum_d q[i,n,h,d] p_w[h*64+d, c]
// qpb[n,h,i] = q . p_b   (q pre-scaled by 0.125 in QKV epilogue)
__global__ void qp_kernel(const u16* __restrict__ qb, const void* __restrict__ p_w,
                          const void* __restrict__ p_b, u16* __restrict__ qp_b,
                          float* __restrict__ qpb, const int* __restrict__ flagp) {
    const int f32 = *flagp;
    int blk = blockIdx.x;                // (n*NH+h)*L + i
    int i = blk & 255;
    int h = (blk >> 8) % NH;
    int n = blk / (256 * NH);
    int t = threadIdx.x;                 // 0..63
    __shared__ float qs[64];
    qs[t] = b2f(qb[(size_t)(i * NB + n) * EMB + h * HD + t]);
    __syncthreads();
    float acc = 0.f;
    #pragma unroll 16
    for (int d = 0; d < 64; ++d)
        acc += qs[d] * ldE(p_w, (size_t)(h * HD + d) * HD + t, f32);
    qp_b[(((size_t)(n * L_SEQ + i)) * 16 + h) * 64 + t] = f2b(acc);
    float v = qs[t] * ldE(p_b, h * HD + t, f32);
    #pragma unroll
    for (int off = 32; off; off >>= 1) v += __shfl_down(v, off);
    if (t == 0) qpb[blk] = v;
}

// S[n,h,i,j] = sum_c qp_b[n,i,h,c] * pos[n,i,j,c] + qpb[n,h,i]
// One wave per (n,i): M=16 (h, 12 used), N=256 (j), K=64 via MFMA 16x16x32.
// B-frags loaded straight from global (wave covers contiguous 2KB per tile).
__global__ __launch_bounds__(256) void s2_mfma(
        const u16* __restrict__ qp_b, const float* __restrict__ qpb,
        const void* __restrict__ pos, float* __restrict__ S,
        const int* __restrict__ flagp) {
    const int f32 = *flagp;
    int wid = (blockIdx.x << 2) + (threadIdx.x >> 6);   // n*L + i
    int i = wid & 255, n = wid >> 8;
    int lane = threadIdx.x & 63;
    int quad = lane >> 4, col = lane & 15;
    // A frags: A[m=col(h)][k=quad*8+jj]
    const u16* qprow = qp_b + (((size_t)wid) * 16 + col) * 64;
    bf16x8 a0 = __builtin_bit_cast(bf16x8, *(const uint4*)(qprow + quad * 8));
    bf16x8 a1 = __builtin_bit_cast(bf16x8, *(const uint4*)(qprow + 32 + quad * 8));
    float qpb_r[4];
    #pragma unroll
    for (int reg = 0; reg < 4; ++reg) {
        int h = quad * 4 + reg;
        qpb_r[reg] = (h < NH) ? qpb[((size_t)n * NH + h) * L_SEQ + i] : 0.f;
    }
    #pragma unroll 4
    for (int t = 0; t < 16; ++t) {
        int j = t * 16 + col;
        size_t pbase = ((size_t)(n * L_SEQ + i) * L_SEQ + j) * HD;
        bf16x8 b0, b1;
        if (f32) {
            const float* pf = (const float*)pos + pbase;
            u16 tmp[16];
            #pragma unroll
            for (int c = 0; c < 8; ++c) tmp[c] = f2b(pf[quad * 8 + c]);
            #pragma unroll
            for (int c = 0; c < 8; ++c) tmp[8 + c] = f2b(pf[32 + quad * 8 + c]);
            b0 = *(bf16x8*)tmp;
            b1 = *(bf16x8*)(tmp + 8);
        } else {
            const u16* pb = (const u16*)pos + pbase;
            b0 = __builtin_bit_cast(bf16x8, *(const uint4*)(pb + quad * 8));
            b1 = __builtin_bit_cast(bf16x8, *(const uint4*)(pb + 32 + quad * 8));
        }
        f32x4 acc = (f32x4){0.f, 0.f, 0.f, 0.f};
        acc = __builtin_amdgcn_mfma_f32_16x16x32_bf16(a0, b0, acc, 0, 0, 0);
        acc = __builtin_amdgcn_mfma_f32_16x16x32_bf16(a1, b1, acc, 0, 0, 0);
        if (quad < 3) {
            #pragma unroll
            for (int reg = 0; reg < 4; ++reg) {
                int h = quad * 4 + reg;   // < 12
                S[(((size_t)n * NH + h) * L_SEQ + i) * L_SEQ + j] = acc[reg] + qpb_r[reg];
            }
        }
    }
}

// scores = q.k + S, softmax, ctx = P@V. Block per (n,h,i), 256 threads.
__global__ __launch_bounds__(256) void attn2_kernel(
        const u16* __restrict__ qb, const u16* __restrict__ kb,
        const u16* __restrict__ vb, const float* __restrict__ S,
        u16* __restrict__ ctxb) {
    int blk = blockIdx.x;                // (n*NH+h)*L + i
    int i = blk & 255;
    int h = (blk >> 8) % NH;
    int n = blk / (256 * NH);
    int j = threadIdx.x;
    __shared__ float qs[64];
    __shared__ float red[256];
    __shared__ float prob[256];
    __shared__ float part[16][68];
    if (j < 64) qs[j] = b2f(qb[(size_t)(i * NB + n) * EMB + h * HD + j]);
    __syncthreads();
    const u16* krow = kb + (size_t)(j * NB + n) * EMB + h * HD;
    float s = S[(size_t)((n * NH + h) * L_SEQ + i) * L_SEQ + j];
    #pragma unroll
    for (int q8 = 0; q8 < 8; ++q8) {
        uint4 u = *(const uint4*)(krow + q8 * 8);
        const float* qq = &qs[q8 * 8];
        s += qq[0] * __uint_as_float(u.x << 16);
        s += qq[1] * __uint_as_float(u.x & 0xFFFF0000u);
        s += qq[2] * __uint_as_float(u.y << 16);
        s += qq[3] * __uint_as_float(u.y & 0xFFFF0000u);
        s += qq[4] * __uint_as_float(u.z << 16);
        s += qq[5] * __uint_as_float(u.z & 0xFFFF0000u);
        s += qq[6] * __uint_as_float(u.w << 16);
        s += qq[7] * __uint_as_float(u.w & 0xFFFF0000u);
    }
    red[j] = s;
    __syncthreads();
    for (int off = 128; off; off >>= 1) {
        if (j < off) red[j] = fmaxf(red[j], red[j + off]);
        __syncthreads();
    }
    float mx = red[0];
    __syncthreads();
    float e = __expf(s - mx);
    red[j] = e;
    __syncthreads();
    for (int off = 128; off; off >>= 1) {
        if (j < off) red[j] += red[j + off];
        __syncthreads();
    }
    prob[j] = e * (1.0f / red[0]);
    __syncthreads();
    int g = j >> 4, d4 = j & 15;
    float ax = 0.f, ay = 0.f, az = 0.f, aw = 0.f;
    #pragma unroll 4
    for (int t = 0; t < 16; ++t) {
        int jj = g * 16 + t;
        float pv = prob[jj];
        uint2 u = *(const uint2*)(vb + (size_t)(jj * NB + n) * EMB + h * HD + d4 * 4);
        ax += pv * __uint_as_float(u.x << 16);
        ay += pv * __uint_as_float(u.x & 0xFFFF0000u);
        az += pv * __uint_as_float(u.y << 16);
        aw += pv * __uint_as_float(u.y & 0xFFFF0000u);
    }
    part[g][d4 * 4 + 0] = ax;
    part[g][d4 * 4 + 1] = ay;
    part[g][d4 * 4 + 2] = az;
    part[g][d4 * 4 + 3] = aw;
    __syncthreads();
    if (j < 64) {
        float v = 0.f;
        #pragma unroll
        for (int g2 = 0; g2 < 16; ++g2) v += part[g2][j];
        ctxb[(size_t)(i * NB + n) * EMB + h * HD + j] = f2b(v);
    }
}

// LayerNorm rows of 768. FINAL=0: write x1f fp32 AND x1b bf16. FINAL=1: d_out runtime.
template <int FINAL>
__global__ void ln_kernel(const float* __restrict__ X, const void* __restrict__ g,
                          const void* __restrict__ b, float* __restrict__ outF,
                          u16* __restrict__ outB, void* __restrict__ outAny,
                          const int* __restrict__ flagp) {
    const int f32 = *flagp;
    int r = blockIdx.x;
    int t = threadIdx.x;
    __shared__ float red[256];
    float x0 = X[(size_t)r * EMB + t];
    float x1 = X[(size_t)r * EMB + t + 256];
    float x2 = X[(size_t)r * EMB + t + 512];
    red[t] = x0 + x1 + x2;
    __syncthreads();
    for (int off = 128; off; off >>= 1) {
        if (t < off) red[t] += red[t + off];
        __syncthreads();
    }
    float mean = red[0] * (1.0f / EMB);
    __syncthreads();
    float d0 = x0 - mean, d1 = x1 - mean, d2 = x2 - mean;
    red[t] = d0 * d0 + d1 * d1 + d2 * d2;
    __syncthreads();
    for (int off = 128; off; off >>= 1) {
        if (t < off) red[t] += red[t + off];
        __syncthreads();
    }
    float rstd = rsqrtf(red[0] * (1.0f / EMB) + 1e-5f);
    float vs[3] = {d0, d1, d2};
    #pragma unroll
    for (int p = 0; p < 3; ++p) {
        int e = t + p * 256;
        float v = vs[p] * rstd * ldE(g, e, f32) + ldE(b, e, f32);
        size_t oi = (size_t)r * EMB + e;
        if (FINAL) {
            if (f32) ((float*)outAny)[oi] = v;
            else     ((bf16*)outAny)[oi] = __float2bfloat16(v);
        } else {
            outF[oi] = v;
            outB[oi] = f2b(v);
        }
    }
}

extern "C" void kernel_launch(void* const* d_in, const int* in_sizes, int n_in,
                              void* d_out, int out_size, void* d_ws, size_t ws_size,
                              hipStream_t stream) {
    const void* src    = d_in[0];
    const void* pos    = d_in[1];
    const void* q_w    = d_in[2];
    const void* q_b    = d_in[3];
    const void* k_w    = d_in[4];
    const void* k_b    = d_in[5];
    const void* v_w    = d_in[6];
    const void* v_b    = d_in[7];
    const void* p_w    = d_in[8];
    const void* p_b    = d_in[9];
    const void* out_w  = d_in[10];
    const void* out_b  = d_in[11];
    const void* lin1_w = d_in[12];
    const void* lin1_b = d_in[13];
    const void* lin2_w = d_in[14];
    const void* lin2_b = d_in[15];
    const void* n1_g   = d_in[16];
    const void* n1_b   = d_in[17];
    const void* n2_g   = d_in[18];
    const void* n2_b   = d_in[19];

    float* f = (float*)d_ws;
    // float-slot layout, ~36.8 MB total
    int*   flagp = (int*)f;                              // 16
    float* biasf = f + 16;                               // 6912
    u16*   xb    = (u16*)(f + 6928);                     // 393216 f
    u16*   wqkv  = (u16*)(f + 400144);                   // 884736 f
    u16*   owb   = (u16*)(f + 1284880);                  // 294912 f
    u16*   l1b   = (u16*)(f + 1579792);                  // 1179648 f
    u16*   l2b   = (u16*)(f + 2759440);                  // 1179648 f
    u16*   qbp   = (u16*)(f + 3939088);                  // 393216 f
    u16*   kbp   = (u16*)(f + 4332304);                  // 393216 f
    u16*   vbp   = (u16*)(f + 4725520);                  // 393216 f
    u16*   qp_b  = (u16*)(f + 5118736);                  // 524288 f  [n][i][16][64]
    float* qpb   = f + 5643024;                          // 12288
    float* S     = f + 5655312;                          // 3145728
    u16*   ctxb  = (u16*)(f + 8801040);                  // 393216 f (end 9194256)
    // overlays:
    u16*   ffb = (u16*)S;                                // 1572864 f (S dead after attn2)
    float* y2  = S + 1572864;                            // 786432 f
    float* y   = S + 2359296;                            // 786432 f
    float* x1f = (float*)qbp;                            // qbp+kbp dead after attn2
    u16*   x1b = vbp;                                    // vbp dead after attn2

    detect_kernel<<<1, 256, 0, stream>>>(src, flagp);

    pack_all<<<3867, 256, 0, stream>>>(xb, wqkv, owb, l1b, l2b, biasf,
                                       src, q_w, k_w, v_w, out_w, lin1_w, lin2_w,
                                       q_b, k_b, v_b, out_b, lin1_b, lin2_b, flagp);

    // QKV fused GEMM (N=2304)
    mfma_gemm<0><<<dim3(18, 8), 256, 0, stream>>>(
        xb, wqkv, biasf, qbp, kbp, vbp, nullptr, nullptr, nullptr, EMB, flagp);

    // position scores
    qp_kernel<<<NB * NH * L_SEQ, 64, 0, stream>>>(qbp, p_w, p_b, qp_b, qpb, flagp);
    s2_mfma<<<NB * L_SEQ / 4, 256, 0, stream>>>(qp_b, qpb, pos, S, flagp);

    // attention
    attn2_kernel<<<NB * NH * L_SEQ, 256, 0, stream>>>(qbp, kbp, vbp, S, ctxb);

    // out projection + residual(src) -> y fp32 ; LN1 -> x1f fp32 + x1b bf16
    mfma_gemm<1><<<dim3(6, 8), 256, 0, stream>>>(
        ctxb, owb, biasf + 2304, nullptr, nullptr, nullptr, y, src, nullptr, EMB, flagp);
    ln_kernel<0><<<1024, 256, 0, stream>>>(y, n1_g, n1_b, x1f, x1b, nullptr, flagp);

    // FF
    mfma_gemm<2><<<dim3(24, 8), 256, 0, stream>>>(
        x1b, l1b, biasf + 3072, ffb, nullptr, nullptr, nullptr, nullptr, nullptr, EMB, flagp);
    mfma_gemm<3><<<dim3(6, 8), 256, 0, stream>>>(
        ffb, l2b, biasf + 6144, nullptr, nullptr, nullptr, y2, nullptr, x1f, DFF, flagp);
    ln_kernel<1><<<1024, 256, 0, stream>>>(y2, n2_g, n2_b, nullptr, nullptr, d_out, flagp);
}

// Round 6
// 366.655 us; speedup vs baseline: 6.2927x; 1.1650x over previous
//
#include <hip/hip_runtime.h>
#include <hip/hip_bf16.h>
#include <math.h>

typedef __hip_bfloat16 bf16;
typedef unsigned short u16;
typedef __attribute__((ext_vector_type(8))) short bf16x8;
typedef __attribute__((ext_vector_type(4))) float f32x4;

#define L_SEQ 256
#define NB 4
#define EMB 768
#define NH 12
#define DFF 3072
#define HD 64

__device__ __forceinline__ float ldE(const void* p, size_t i, int f32) {
    return f32 ? ((const float*)p)[i] : __bfloat162float(((const bf16*)p)[i]);
}
__device__ __forceinline__ float b2f(u16 v) { return __uint_as_float(((unsigned)v) << 16); }
__device__ __forceinline__ u16 f2b(float v) {
    bf16 h = __float2bfloat16(v);
    return *(u16*)&h;
}

// Runtime input dtype detect: fp32 words read as bf16 halves -> huge exponents.
__global__ void detect_kernel(const void* __restrict__ src, int* __restrict__ flagp) {
    __shared__ int cnt[256];
    int t = threadIdx.x;
    unsigned w = ((const unsigned*)src)[t];
    unsigned e = ((w & 0xFFFFu) >> 7) & 0xFFu;
    cnt[t] = (e >= 0xC3u) ? 1 : 0;
    __syncthreads();
    for (int off = 128; off; off >>= 1) {
        if (t < off) cnt[t] += cnt[t + off];
        __syncthreads();
    }
    if (t == 0) *flagp = (cnt[0] > 8) ? 1 : 0;
}

__device__ __forceinline__ void cvt8(u16* dst, const void* s, size_t off, int f32) {
    if (f32) {
        const float* sf = (const float*)s + off;
        #pragma unroll
        for (int t = 0; t < 8; ++t) dst[t] = f2b(sf[t]);
    } else {
        *(uint4*)dst = *(const uint4*)((const u16*)s + off);
    }
}

// One kernel packs ALL weights/activations to bf16 and all biases to fp32.
__global__ void pack_all(u16* __restrict__ xb, u16* __restrict__ wqkv,
                         u16* __restrict__ owb, u16* __restrict__ l1b,
                         u16* __restrict__ l2b, float* __restrict__ biasf,
                         const void* src, const void* qw, const void* kw, const void* vw,
                         const void* ow, const void* l1w, const void* l2w,
                         const void* qb, const void* kb, const void* vb,
                         const void* ob, const void* b1, const void* b2,
                         const int* __restrict__ flagp) {
    const int f32 = *flagp;
    int b = blockIdx.x;
    if (b >= 3840) {
        int o = (b - 3840) * 256 + threadIdx.x;
        if (o >= 6912) return;
        float v;
        if (o < 768)       v = ldE(qb, o, f32);
        else if (o < 1536) v = ldE(kb, o - 768, f32);
        else if (o < 2304) v = ldE(vb, o - 1536, f32);
        else if (o < 3072) v = ldE(ob, o - 2304, f32);
        else if (o < 6144) v = ldE(b1, o - 3072, f32);
        else               v = ldE(b2, o - 6144, f32);
        biasf[o] = v;
        return;
    }
    int gid = b * 256 + threadIdx.x;
    u16 tmp[8];
    if (gid < 98304) {
        size_t idx = (size_t)gid * 8;
        cvt8(tmp, src, idx, f32);
        *(uint4*)(xb + idx) = *(uint4*)tmp;
    } else if (gid < 319488) {
        size_t idx = (size_t)(gid - 98304) * 8;
        int r = (int)(idx / EMB);
        const void* s;
        size_t off;
        if (r < EMB)          { s = qw; off = idx; }
        else if (r < 2 * EMB) { s = kw; off = idx - (size_t)EMB * EMB; }
        else                  { s = vw; off = idx - (size_t)2 * EMB * EMB; }
        cvt8(tmp, s, off, f32);
        *(uint4*)(wqkv + idx) = *(uint4*)tmp;
    } else if (gid < 393216) {
        size_t idx = (size_t)(gid - 319488) * 8;
        cvt8(tmp, ow, idx, f32);
        *(uint4*)(owb + idx) = *(uint4*)tmp;
    } else if (gid < 688128) {
        size_t idx = (size_t)(gid - 393216) * 8;
        cvt8(tmp, l1w, idx, f32);
        *(uint4*)(l1b + idx) = *(uint4*)tmp;
    } else {
        size_t idx = (size_t)(gid - 688128) * 8;
        cvt8(tmp, l2w, idx, f32);
        *(uint4*)(l2b + idx) = *(uint4*)tmp;
    }
}

// MFMA bf16 GEMM: C[M,N] = A[M,K] @ W[N,K]^T (+bias, epilogue per MODE).
// 128x128 tile, 4 waves, each 64x64 via 4x4 16x16x32 frags. M=1024 always.
// MODE 0: qkv split -> q,k bf16 row-major (q scaled 0.125); V written TRANSPOSED
//         vt[(n*EMB+e)*L_SEQ+i]
// MODE 1: + residE (runtime dtype) -> outF fp32, stride EMB
// MODE 2: GELU -> outB0 bf16, stride DFF
// MODE 3: + residF fp32 -> outF fp32, stride EMB
template <int MODE>
__global__ __launch_bounds__(256) void mfma_gemm(
        const u16* __restrict__ A, const u16* __restrict__ W,
        const float* __restrict__ biasf,
        u16* __restrict__ outB0, u16* __restrict__ outB1, u16* __restrict__ outB2,
        float* __restrict__ outF, const void* __restrict__ residE,
        const float* __restrict__ residF, int K, const int* __restrict__ flagp) {
    __shared__ u16 As[128][40];
    __shared__ u16 Ws[128][40];
    int tid = threadIdx.x;
    int wave = tid >> 6, lane = tid & 63;
    int quad = lane >> 4, col = lane & 15;
    int m0 = blockIdx.y * 128, n0 = blockIdx.x * 128;
    int wm = (wave >> 1) * 64, wn = (wave & 1) * 64;
    f32x4 acc[4][4];
    #pragma unroll
    for (int a = 0; a < 4; ++a)
        #pragma unroll
        for (int b = 0; b < 4; ++b) acc[a][b] = (f32x4){0.f, 0.f, 0.f, 0.f};
    for (int k0 = 0; k0 < K; k0 += 32) {
        #pragma unroll
        for (int it = 0; it < 2; ++it) {
            int l = tid + it * 256;
            int r = l >> 2, c4 = (l & 3) * 8;
            *(uint4*)&As[r][c4] = *(const uint4*)&A[(size_t)(m0 + r) * K + k0 + c4];
            *(uint4*)&Ws[r][c4] = *(const uint4*)&W[(size_t)(n0 + r) * K + k0 + c4];
        }
        __syncthreads();
        bf16x8 af[4], bfr[4];
        #pragma unroll
        for (int mi = 0; mi < 4; ++mi)
            af[mi] = __builtin_bit_cast(bf16x8, *(const uint4*)&As[wm + mi * 16 + col][quad * 8]);
        #pragma unroll
        for (int ni = 0; ni < 4; ++ni)
            bfr[ni] = __builtin_bit_cast(bf16x8, *(const uint4*)&Ws[wn + ni * 16 + col][quad * 8]);
        #pragma unroll
        for (int mi = 0; mi < 4; ++mi)
            #pragma unroll
            for (int ni = 0; ni < 4; ++ni)
                acc[mi][ni] = __builtin_amdgcn_mfma_f32_16x16x32_bf16(
                    af[mi], bfr[ni], acc[mi][ni], 0, 0, 0);
        __syncthreads();
    }
    const int f32 = *flagp;
    #pragma unroll
    for (int mi = 0; mi < 4; ++mi)
        #pragma unroll
        for (int ni = 0; ni < 4; ++ni)
            #pragma unroll
            for (int reg = 0; reg < 4; ++reg) {
                int rr = m0 + wm + mi * 16 + quad * 4 + reg;
                int cc = n0 + wn + ni * 16 + col;
                float v = acc[mi][ni][reg] + biasf[cc];
                if (MODE == 0) {
                    if (cc < EMB) {
                        outB0[(size_t)rr * EMB + cc] = f2b(v * 0.125f);
                    } else if (cc < 2 * EMB) {
                        outB1[(size_t)rr * EMB + cc - EMB] = f2b(v);
                    } else {
                        // vt[(n*EMB + e)*L + i], rr = i*NB + n
                        outB2[((size_t)(rr & 3) * EMB + (cc - 2 * EMB)) * L_SEQ + (rr >> 2)] = f2b(v);
                    }
                } else if (MODE == 1) {
                    v += ldE(residE, (size_t)rr * EMB + cc, f32);
                    outF[(size_t)rr * EMB + cc] = v;
                } else if (MODE == 2) {
                    v = 0.5f * v * (1.0f + erff(v * 0.70710678118654752f));
                    outB0[(size_t)rr * DFF + cc] = f2b(v);
                } else {
                    v += residF[(size_t)rr * EMB + cc];
                    outF[(size_t)rr * EMB + cc] = v;
                }
            }
}

// qp_b[n,i,h,c] (bf16, h padded to 16) = sum_d q[i,n,h,d] p_w[h*64+d, c]
// qpb[n,h,i] = q . p_b   (q pre-scaled by 0.125 in QKV epilogue)
__global__ void qp_kernel(const u16* __restrict__ qb, const void* __restrict__ p_w,
                          const void* __restrict__ p_b, u16* __restrict__ qp_b,
                          float* __restrict__ qpb, const int* __restrict__ flagp) {
    const int f32 = *flagp;
    int blk = blockIdx.x;                // (n*NH+h)*L + i
    int i = blk & 255;
    int h = (blk >> 8) % NH;
    int n = blk / (256 * NH);
    int t = threadIdx.x;                 // 0..63
    __shared__ float qs[64];
    qs[t] = b2f(qb[(size_t)(i * NB + n) * EMB + h * HD + t]);
    __syncthreads();
    float acc = 0.f;
    #pragma unroll 16
    for (int d = 0; d < 64; ++d)
        acc += qs[d] * ldE(p_w, (size_t)(h * HD + d) * HD + t, f32);
    qp_b[(((size_t)(n * L_SEQ + i)) * 16 + h) * 64 + t] = f2b(acc);
    float v = qs[t] * ldE(p_b, h * HD + t, f32);
    #pragma unroll
    for (int off = 32; off; off >>= 1) v += __shfl_down(v, off);
    if (t == 0) qpb[blk] = v;
}

// S[n,h,i,j] = sum_c qp_b[n,i,h,c] * pos[n,i,j,c] + qpb[n,h,i]
__global__ __launch_bounds__(256) void s2_mfma(
        const u16* __restrict__ qp_b, const float* __restrict__ qpb,
        const void* __restrict__ pos, float* __restrict__ S,
        const int* __restrict__ flagp) {
    const int f32 = *flagp;
    int wid = (blockIdx.x << 2) + (threadIdx.x >> 6);   // n*L + i
    int i = wid & 255, n = wid >> 8;
    int lane = threadIdx.x & 63;
    int quad = lane >> 4, col = lane & 15;
    const u16* qprow = qp_b + (((size_t)wid) * 16 + col) * 64;
    bf16x8 a0 = __builtin_bit_cast(bf16x8, *(const uint4*)(qprow + quad * 8));
    bf16x8 a1 = __builtin_bit_cast(bf16x8, *(const uint4*)(qprow + 32 + quad * 8));
    float qpb_r[4];
    #pragma unroll
    for (int reg = 0; reg < 4; ++reg) {
        int h = quad * 4 + reg;
        qpb_r[reg] = (h < NH) ? qpb[((size_t)n * NH + h) * L_SEQ + i] : 0.f;
    }
    #pragma unroll 4
    for (int t = 0; t < 16; ++t) {
        int j = t * 16 + col;
        size_t pbase = ((size_t)(n * L_SEQ + i) * L_SEQ + j) * HD;
        bf16x8 b0, b1;
        if (f32) {
            const float* pf = (const float*)pos + pbase;
            u16 tmp[16];
            #pragma unroll
            for (int c = 0; c < 8; ++c) tmp[c] = f2b(pf[quad * 8 + c]);
            #pragma unroll
            for (int c = 0; c < 8; ++c) tmp[8 + c] = f2b(pf[32 + quad * 8 + c]);
            b0 = *(bf16x8*)tmp;
            b1 = *(bf16x8*)(tmp + 8);
        } else {
            const u16* pb = (const u16*)pos + pbase;
            b0 = __builtin_bit_cast(bf16x8, *(const uint4*)(pb + quad * 8));
            b1 = __builtin_bit_cast(bf16x8, *(const uint4*)(pb + 32 + quad * 8));
        }
        f32x4 acc = (f32x4){0.f, 0.f, 0.f, 0.f};
        acc = __builtin_amdgcn_mfma_f32_16x16x32_bf16(a0, b0, acc, 0, 0, 0);
        acc = __builtin_amdgcn_mfma_f32_16x16x32_bf16(a1, b1, acc, 0, 0, 0);
        if (quad < 3) {
            #pragma unroll
            for (int reg = 0; reg < 4; ++reg) {
                int h = quad * 4 + reg;
                S[(((size_t)n * NH + h) * L_SEQ + i) * L_SEQ + j] = acc[reg] + qpb_r[reg];
            }
        }
    }
}

// MFMA attention: scores = q.k^T + S, softmax (register+shuffle), ctx = P@V.
// Block per (n,h,it): 4 waves, wave owns 16 i-rows. No __syncthreads at all.
__global__ __launch_bounds__(256) void attn3_kernel(
        const u16* __restrict__ qb, const u16* __restrict__ kb,
        const u16* __restrict__ vt, const float* __restrict__ S,
        u16* __restrict__ ctxb) {
    __shared__ u16 p_lds[4][16][268];    // pad 256->268: 2-way (free) b128 reads
    int b = blockIdx.x;
    int n = b / 48, rem = b % 48, h = rem >> 2, it = rem & 3;
    int wave = threadIdx.x >> 6, lane = threadIdx.x & 63;
    int quad = lane >> 4, col = lane & 15;
    int i0 = it * 64 + wave * 16;

    // A-frags: q rows i0..i0+15 (m = col)
    const u16* qrow = qb + ((size_t)(i0 + col) * NB + n) * EMB + h * HD;
    bf16x8 a0 = __builtin_bit_cast(bf16x8, *(const uint4*)(qrow + quad * 8));
    bf16x8 a1 = __builtin_bit_cast(bf16x8, *(const uint4*)(qrow + 32 + quad * 8));

    // QK^T over 16 j-tiles
    f32x4 sc[16];
    #pragma unroll
    for (int t = 0; t < 16; ++t) {
        const u16* krow = kb + ((size_t)(t * 16 + col) * NB + n) * EMB + h * HD;
        bf16x8 b0 = __builtin_bit_cast(bf16x8, *(const uint4*)(krow + quad * 8));
        bf16x8 b1 = __builtin_bit_cast(bf16x8, *(const uint4*)(krow + 32 + quad * 8));
        f32x4 acc = (f32x4){0.f, 0.f, 0.f, 0.f};
        acc = __builtin_amdgcn_mfma_f32_16x16x32_bf16(a0, b0, acc, 0, 0, 0);
        acc = __builtin_amdgcn_mfma_f32_16x16x32_bf16(a1, b1, acc, 0, 0, 0);
        sc[t] = acc;
    }

    // + S, softmax per row (row = i0 + quad*4 + reg; cols on 16 lanes x 16 tiles)
    #pragma unroll
    for (int reg = 0; reg < 4; ++reg) {
        const float* Srow = S + (((size_t)n * NH + h) * L_SEQ + i0 + quad * 4 + reg) * L_SEQ + col;
        float m = -1e30f;
        #pragma unroll
        for (int t = 0; t < 16; ++t) {
            float v = sc[t][reg] + Srow[t * 16];
            sc[t][reg] = v;
            m = fmaxf(m, v);
        }
        #pragma unroll
        for (int off = 1; off < 16; off <<= 1) m = fmaxf(m, __shfl_xor(m, off));
        float sum = 0.f;
        #pragma unroll
        for (int t = 0; t < 16; ++t) {
            float e = __expf(sc[t][reg] - m);
            sc[t][reg] = e;
            sum += e;
        }
        #pragma unroll
        for (int off = 1; off < 16; off <<= 1) sum += __shfl_xor(sum, off);
        float inv = 1.0f / sum;
        #pragma unroll
        for (int t = 0; t < 16; ++t)
            p_lds[wave][quad * 4 + reg][t * 16 + col] = f2b(sc[t][reg] * inv);
    }

    // PV: A = P (LDS, m=col), B = vt rows (n=d, k=j)
    bf16x8 ap[8];
    #pragma unroll
    for (int kt = 0; kt < 8; ++kt)
        ap[kt] = __builtin_bit_cast(bf16x8, *(const uint4*)&p_lds[wave][col][kt * 32 + quad * 8]);
    #pragma unroll
    for (int nt = 0; nt < 4; ++nt) {
        const u16* vrow = vt + ((size_t)n * EMB + h * HD + nt * 16 + col) * L_SEQ;
        f32x4 acc = (f32x4){0.f, 0.f, 0.f, 0.f};
        #pragma unroll
        for (int kt = 0; kt < 8; ++kt) {
            bf16x8 bp = __builtin_bit_cast(bf16x8, *(const uint4*)(vrow + kt * 32 + quad * 8));
            acc = __builtin_amdgcn_mfma_f32_16x16x32_bf16(ap[kt], bp, acc, 0, 0, 0);
        }
        #pragma unroll
        for (int reg = 0; reg < 4; ++reg) {
            int ii = i0 + quad * 4 + reg;
            ctxb[((size_t)ii * NB + n) * EMB + h * HD + nt * 16 + col] = f2b(acc[reg]);
        }
    }
}

// LayerNorm rows of 768. FINAL=0: write x1f fp32 AND x1b bf16. FINAL=1: d_out runtime.
template <int FINAL>
__global__ void ln_kernel(const float* __restrict__ X, const void* __restrict__ g,
                          const void* __restrict__ b, float* __restrict__ outF,
                          u16* __restrict__ outB, void* __restrict__ outAny,
                          const int* __restrict__ flagp) {
    const int f32 = *flagp;
    int r = blockIdx.x;
    int t = threadIdx.x;
    __shared__ float red[256];
    float x0 = X[(size_t)r * EMB + t];
    float x1 = X[(size_t)r * EMB + t + 256];
    float x2 = X[(size_t)r * EMB + t + 512];
    red[t] = x0 + x1 + x2;
    __syncthreads();
    for (int off = 128; off; off >>= 1) {
        if (t < off) red[t] += red[t + off];
        __syncthreads();
    }
    float mean = red[0] * (1.0f / EMB);
    __syncthreads();
    float d0 = x0 - mean, d1 = x1 - mean, d2 = x2 - mean;
    red[t] = d0 * d0 + d1 * d1 + d2 * d2;
    __syncthreads();
    for (int off = 128; off; off >>= 1) {
        if (t < off) red[t] += red[t + off];
        __syncthreads();
    }
    float rstd = rsqrtf(red[0] * (1.0f / EMB) + 1e-5f);
    float vs[3] = {d0, d1, d2};
    #pragma unroll
    for (int p = 0; p < 3; ++p) {
        int e = t + p * 256;
        float v = vs[p] * rstd * ldE(g, e, f32) + ldE(b, e, f32);
        size_t oi = (size_t)r * EMB + e;
        if (FINAL) {
            if (f32) ((float*)outAny)[oi] = v;
            else     ((bf16*)outAny)[oi] = __float2bfloat16(v);
        } else {
            outF[oi] = v;
            outB[oi] = f2b(v);
        }
    }
}

extern "C" void kernel_launch(void* const* d_in, const int* in_sizes, int n_in,
                              void* d_out, int out_size, void* d_ws, size_t ws_size,
                              hipStream_t stream) {
    const void* src    = d_in[0];
    const void* pos    = d_in[1];
    const void* q_w    = d_in[2];
    const void* q_b    = d_in[3];
    const void* k_w    = d_in[4];
    const void* k_b    = d_in[5];
    const void* v_w    = d_in[6];
    const void* v_b    = d_in[7];
    const void* p_w    = d_in[8];
    const void* p_b    = d_in[9];
    const void* out_w  = d_in[10];
    const void* out_b  = d_in[11];
    const void* lin1_w = d_in[12];
    const void* lin1_b = d_in[13];
    const void* lin2_w = d_in[14];
    const void* lin2_b = d_in[15];
    const void* n1_g   = d_in[16];
    const void* n1_b   = d_in[17];
    const void* n2_g   = d_in[18];
    const void* n2_b   = d_in[19];

    float* f = (float*)d_ws;
    int*   flagp = (int*)f;                              // 16
    float* biasf = f + 16;                               // 6912
    u16*   xb    = (u16*)(f + 6928);                     // 393216 f
    u16*   wqkv  = (u16*)(f + 400144);                   // 884736 f
    u16*   owb   = (u16*)(f + 1284880);                  // 294912 f
    u16*   l1b   = (u16*)(f + 1579792);                  // 1179648 f
    u16*   l2b   = (u16*)(f + 2759440);                  // 1179648 f
    u16*   qbp   = (u16*)(f + 3939088);                  // 393216 f
    u16*   kbp   = (u16*)(f + 4332304);                  // 393216 f
    u16*   vtb   = (u16*)(f + 4725520);                  // 393216 f  vt[n][e][i]
    u16*   qp_b  = (u16*)(f + 5118736);                  // 524288 f
    float* qpb   = f + 5643024;                          // 12288
    float* S     = f + 5655312;                          // 3145728
    u16*   ctxb  = (u16*)(f + 8801040);                  // 393216 f
    // overlays:
    u16*   ffb = (u16*)S;                                // S dead after attn3
    float* y2  = S + 1572864;
    float* y   = S + 2359296;
    float* x1f = (float*)qbp;                            // q/k dead after attn3
    u16*   x1b = vtb;                                    // vt dead after attn3

    detect_kernel<<<1, 256, 0, stream>>>(src, flagp);

    pack_all<<<3867, 256, 0, stream>>>(xb, wqkv, owb, l1b, l2b, biasf,
                                       src, q_w, k_w, v_w, out_w, lin1_w, lin2_w,
                                       q_b, k_b, v_b, out_b, lin1_b, lin2_b, flagp);

    // QKV fused GEMM (N=2304); V written transposed
    mfma_gemm<0><<<dim3(18, 8), 256, 0, stream>>>(
        xb, wqkv, biasf, qbp, kbp, vtb, nullptr, nullptr, nullptr, EMB, flagp);

    // position scores
    qp_kernel<<<NB * NH * L_SEQ, 64, 0, stream>>>(qbp, p_w, p_b, qp_b, qpb, flagp);
    s2_mfma<<<NB * L_SEQ / 4, 256, 0, stream>>>(qp_b, qpb, pos, S, flagp);

    // MFMA attention
    attn3_kernel<<<NB * NH * 4, 256, 0, stream>>>(qbp, kbp, vtb, S, ctxb);

    // out projection + residual(src) -> y fp32 ; LN1 -> x1f fp32 + x1b bf16
    mfma_gemm<1><<<dim3(6, 8), 256, 0, stream>>>(
        ctxb, owb, biasf + 2304, nullptr, nullptr, nullptr, y, src, nullptr, EMB, flagp);
    ln_kernel<0><<<1024, 256, 0, stream>>>(y, n1_g, n1_b, x1f, x1b, nullptr, flagp);

    // FF
    mfma_gemm<2><<<dim3(24, 8), 256, 0, stream>>>(
        x1b, l1b, biasf + 3072, ffb, nullptr, nullptr, nullptr, nullptr, nullptr, EMB, flagp);
    mfma_gemm<3><<<dim3(6, 8), 256, 0, stream>>>(
        ffb, l2b, biasf + 6144, nullptr, nullptr, nullptr, y2, nullptr, x1f, DFF, flagp);
    ln_kernel<1><<<1024, 256, 0, stream>>>(y2, n2_g, n2_b, nullptr, nullptr, d_out, flagp);
}

// Round 7
// 309.643 us; speedup vs baseline: 7.4513x; 1.1841x over previous
//
#include <hip/hip_runtime.h>
#include <hip/hip_bf16.h>
#include <math.h>

typedef __hip_bfloat16 bf16;
typedef unsigned short u16;
typedef __attribute__((ext_vector_type(8))) short bf16x8;
typedef __attribute__((ext_vector_type(4))) float f32x4;

#define L_SEQ 256
#define NB 4
#define EMB 768
#define NH 12
#define DFF 3072
#define HD 64

__device__ __forceinline__ float ldE(const void* p, size_t i, int f32) {
    return f32 ? ((const float*)p)[i] : __bfloat162float(((const bf16*)p)[i]);
}
__device__ __forceinline__ float b2f(u16 v) { return __uint_as_float(((unsigned)v) << 16); }
__device__ __forceinline__ u16 f2b(float v) {
    bf16 h = __float2bfloat16(v);
    return *(u16*)&h;
}

// Runtime input dtype detect: fp32 words read as bf16 halves -> huge exponents.
__global__ void detect_kernel(const void* __restrict__ src, int* __restrict__ flagp) {
    __shared__ int cnt[256];
    int t = threadIdx.x;
    unsigned w = ((const unsigned*)src)[t];
    unsigned e = ((w & 0xFFFFu) >> 7) & 0xFFu;
    cnt[t] = (e >= 0xC3u) ? 1 : 0;
    __syncthreads();
    for (int off = 128; off; off >>= 1) {
        if (t < off) cnt[t] += cnt[t + off];
        __syncthreads();
    }
    if (t == 0) *flagp = (cnt[0] > 8) ? 1 : 0;
}

__device__ __forceinline__ void cvt8(u16* dst, const void* s, size_t off, int f32) {
    if (f32) {
        const float* sf = (const float*)s + off;
        #pragma unroll
        for (int t = 0; t < 8; ++t) dst[t] = f2b(sf[t]);
    } else {
        *(uint4*)dst = *(const uint4*)((const u16*)s + off);
    }
}

// One kernel packs ALL weights/activations to bf16 and all biases to fp32.
__global__ void pack_all(u16* __restrict__ xb, u16* __restrict__ wqkv,
                         u16* __restrict__ owb, u16* __restrict__ l1b,
                         u16* __restrict__ l2b, float* __restrict__ biasf,
                         const void* src, const void* qw, const void* kw, const void* vw,
                         const void* ow, const void* l1w, const void* l2w,
                         const void* qb, const void* kb, const void* vb,
                         const void* ob, const void* b1, const void* b2,
                         const int* __restrict__ flagp) {
    const int f32 = *flagp;
    int b = blockIdx.x;
    if (b >= 3840) {
        int o = (b - 3840) * 256 + threadIdx.x;
        if (o >= 6912) return;
        float v;
        if (o < 768)       v = ldE(qb, o, f32);
        else if (o < 1536) v = ldE(kb, o - 768, f32);
        else if (o < 2304) v = ldE(vb, o - 1536, f32);
        else if (o < 3072) v = ldE(ob, o - 2304, f32);
        else if (o < 6144) v = ldE(b1, o - 3072, f32);
        else               v = ldE(b2, o - 6144, f32);
        biasf[o] = v;
        return;
    }
    int gid = b * 256 + threadIdx.x;
    u16 tmp[8];
    if (gid < 98304) {
        size_t idx = (size_t)gid * 8;
        cvt8(tmp, src, idx, f32);
        *(uint4*)(xb + idx) = *(uint4*)tmp;
    } else if (gid < 319488) {
        size_t idx = (size_t)(gid - 98304) * 8;
        int r = (int)(idx / EMB);
        const void* s;
        size_t off;
        if (r < EMB)          { s = qw; off = idx; }
        else if (r < 2 * EMB) { s = kw; off = idx - (size_t)EMB * EMB; }
        else                  { s = vw; off = idx - (size_t)2 * EMB * EMB; }
        cvt8(tmp, s, off, f32);
        *(uint4*)(wqkv + idx) = *(uint4*)tmp;
    } else if (gid < 393216) {
        size_t idx = (size_t)(gid - 319488) * 8;
        cvt8(tmp, ow, idx, f32);
        *(uint4*)(owb + idx) = *(uint4*)tmp;
    } else if (gid < 688128) {
        size_t idx = (size_t)(gid - 393216) * 8;
        cvt8(tmp, l1w, idx, f32);
        *(uint4*)(l1b + idx) = *(uint4*)tmp;
    } else {
        size_t idx = (size_t)(gid - 688128) * 8;
        cvt8(tmp, l2w, idx, f32);
        *(uint4*)(l2b + idx) = *(uint4*)tmp;
    }
}

// MFMA bf16 GEMM: C[M,N] = A[M,K] @ W[N,K]^T. 128x128 tile, 4 waves.
// lda = row stride of A and W; loop bound K; split-K offset = blockIdx.z*ksplit.
// MODE 0: +bias, qkv split -> q,k bf16 (q scaled 0.125); V TRANSPOSED vt[n][e][i]
// MODE 2: +bias, GELU -> outB0 bf16, stride DFF
// MODE 4: partial (no bias) -> fp32 to (z ? outF2 : outF)
// MODE 5: partial (no bias) -> atomicAdd into outF
template <int MODE>
__global__ __launch_bounds__(256) void mfma_gemm(
        const u16* __restrict__ A, const u16* __restrict__ W,
        const float* __restrict__ biasf,
        u16* __restrict__ outB0, u16* __restrict__ outB1, u16* __restrict__ outB2,
        float* __restrict__ outF, float* __restrict__ outF2,
        int K, int lda, int ksplit) {
    __shared__ u16 As[128][40];
    __shared__ u16 Ws[128][40];
    int tid = threadIdx.x;
    int wave = tid >> 6, lane = tid & 63;
    int quad = lane >> 4, col = lane & 15;
    int m0 = blockIdx.y * 128, n0 = blockIdx.x * 128;
    int z = blockIdx.z;
    const u16* Ap = A + (size_t)z * ksplit;
    const u16* Wp = W + (size_t)z * ksplit;
    int wm = (wave >> 1) * 64, wn = (wave & 1) * 64;
    f32x4 acc[4][4];
    #pragma unroll
    for (int a = 0; a < 4; ++a)
        #pragma unroll
        for (int b = 0; b < 4; ++b) acc[a][b] = (f32x4){0.f, 0.f, 0.f, 0.f};
    for (int k0 = 0; k0 < K; k0 += 32) {
        #pragma unroll
        for (int it = 0; it < 2; ++it) {
            int l = tid + it * 256;
            int r = l >> 2, c4 = (l & 3) * 8;
            *(uint4*)&As[r][c4] = *(const uint4*)&Ap[(size_t)(m0 + r) * lda + k0 + c4];
            *(uint4*)&Ws[r][c4] = *(const uint4*)&Wp[(size_t)(n0 + r) * lda + k0 + c4];
        }
        __syncthreads();
        bf16x8 af[4], bfr[4];
        #pragma unroll
        for (int mi = 0; mi < 4; ++mi)
            af[mi] = __builtin_bit_cast(bf16x8, *(const uint4*)&As[wm + mi * 16 + col][quad * 8]);
        #pragma unroll
        for (int ni = 0; ni < 4; ++ni)
            bfr[ni] = __builtin_bit_cast(bf16x8, *(const uint4*)&Ws[wn + ni * 16 + col][quad * 8]);
        #pragma unroll
        for (int mi = 0; mi < 4; ++mi)
            #pragma unroll
            for (int ni = 0; ni < 4; ++ni)
                acc[mi][ni] = __builtin_amdgcn_mfma_f32_16x16x32_bf16(
                    af[mi], bfr[ni], acc[mi][ni], 0, 0, 0);
        __syncthreads();
    }
    #pragma unroll
    for (int mi = 0; mi < 4; ++mi)
        #pragma unroll
        for (int ni = 0; ni < 4; ++ni)
            #pragma unroll
            for (int reg = 0; reg < 4; ++reg) {
                int rr = m0 + wm + mi * 16 + quad * 4 + reg;
                int cc = n0 + wn + ni * 16 + col;
                float v = acc[mi][ni][reg];
                if (MODE == 0) {
                    v += biasf[cc];
                    if (cc < EMB) {
                        outB0[(size_t)rr * EMB + cc] = f2b(v * 0.125f);
                    } else if (cc < 2 * EMB) {
                        outB1[(size_t)rr * EMB + cc - EMB] = f2b(v);
                    } else {
                        // vt[(n*EMB + e)*L + i], rr = i*NB + n
                        outB2[((size_t)(rr & 3) * EMB + (cc - 2 * EMB)) * L_SEQ + (rr >> 2)] = f2b(v);
                    }
                } else if (MODE == 2) {
                    v += biasf[cc];
                    v = 0.5f * v * (1.0f + erff(v * 0.70710678118654752f));
                    outB0[(size_t)rr * DFF + cc] = f2b(v);
                } else if (MODE == 4) {
                    float* o = z ? outF2 : outF;
                    o[(size_t)rr * EMB + cc] = v;
                } else {
                    atomicAdd(&outF[(size_t)rr * EMB + cc], v);
                }
            }
}

// qp_b[n,i,h,c] (bf16, h padded to 16) = sum_d q[i,n,h,d] p_w[h*64+d, c]
// qpb[n,h,i] = q . p_b   (q pre-scaled by 0.125 in QKV epilogue)
__global__ void qp_kernel(const u16* __restrict__ qb, const void* __restrict__ p_w,
                          const void* __restrict__ p_b, u16* __restrict__ qp_b,
                          float* __restrict__ qpb, const int* __restrict__ flagp) {
    const int f32 = *flagp;
    int blk = blockIdx.x;                // (n*NH+h)*L + i
    int i = blk & 255;
    int h = (blk >> 8) % NH;
    int n = blk / (256 * NH);
    int t = threadIdx.x;                 // 0..63
    __shared__ float qs[64];
    qs[t] = b2f(qb[(size_t)(i * NB + n) * EMB + h * HD + t]);
    __syncthreads();
    float acc = 0.f;
    #pragma unroll 16
    for (int d = 0; d < 64; ++d)
        acc += qs[d] * ldE(p_w, (size_t)(h * HD + d) * HD + t, f32);
    qp_b[(((size_t)(n * L_SEQ + i)) * 16 + h) * 64 + t] = f2b(acc);
    float v = qs[t] * ldE(p_b, h * HD + t, f32);
    #pragma unroll
    for (int off = 32; off; off >>= 1) v += __shfl_down(v, off);
    if (t == 0) qpb[blk] = v;
}

// S[n,h,i,j] = sum_c qp_b[n,i,h,c] * pos[n,i,j,c] + qpb[n,h,i]
__global__ __launch_bounds__(256) void s2_mfma(
        const u16* __restrict__ qp_b, const float* __restrict__ qpb,
        const void* __restrict__ pos, float* __restrict__ S,
        const int* __restrict__ flagp) {
    const int f32 = *flagp;
    int wid = (blockIdx.x << 2) + (threadIdx.x >> 6);   // n*L + i
    int i = wid & 255, n = wid >> 8;
    int lane = threadIdx.x & 63;
    int quad = lane >> 4, col = lane & 15;
    const u16* qprow = qp_b + (((size_t)wid) * 16 + col) * 64;
    bf16x8 a0 = __builtin_bit_cast(bf16x8, *(const uint4*)(qprow + quad * 8));
    bf16x8 a1 = __builtin_bit_cast(bf16x8, *(const uint4*)(qprow + 32 + quad * 8));
    float qpb_r[4];
    #pragma unroll
    for (int reg = 0; reg < 4; ++reg) {
        int h = quad * 4 + reg;
        qpb_r[reg] = (h < NH) ? qpb[((size_t)n * NH + h) * L_SEQ + i] : 0.f;
    }
    #pragma unroll 4
    for (int t = 0; t < 16; ++t) {
        int j = t * 16 + col;
        size_t pbase = ((size_t)(n * L_SEQ + i) * L_SEQ + j) * HD;
        bf16x8 b0, b1;
        if (f32) {
            const float* pf = (const float*)pos + pbase;
            u16 tmp[16];
            #pragma unroll
            for (int c = 0; c < 8; ++c) tmp[c] = f2b(pf[quad * 8 + c]);
            #pragma unroll
            for (int c = 0; c < 8; ++c) tmp[8 + c] = f2b(pf[32 + quad * 8 + c]);
            b0 = *(bf16x8*)tmp;
            b1 = *(bf16x8*)(tmp + 8);
        } else {
            const u16* pb = (const u16*)pos + pbase;
            b0 = __builtin_bit_cast(bf16x8, *(const uint4*)(pb + quad * 8));
            b1 = __builtin_bit_cast(bf16x8, *(const uint4*)(pb + 32 + quad * 8));
        }
        f32x4 acc = (f32x4){0.f, 0.f, 0.f, 0.f};
        acc = __builtin_amdgcn_mfma_f32_16x16x32_bf16(a0, b0, acc, 0, 0, 0);
        acc = __builtin_amdgcn_mfma_f32_16x16x32_bf16(a1, b1, acc, 0, 0, 0);
        if (quad < 3) {
            #pragma unroll
            for (int reg = 0; reg < 4; ++reg) {
                int h = quad * 4 + reg;
                S[(((size_t)n * NH + h) * L_SEQ + i) * L_SEQ + j] = acc[reg] + qpb_r[reg];
            }
        }
    }
}

// MFMA attention: scores = q.k^T + S, softmax (register+shuffle), ctx = P@V.
__global__ __launch_bounds__(256) void attn3_kernel(
        const u16* __restrict__ qb, const u16* __restrict__ kb,
        const u16* __restrict__ vt, const float* __restrict__ S,
        u16* __restrict__ ctxb) {
    __shared__ u16 p_lds[4][16][268];
    int b = blockIdx.x;
    int n = b / 48, rem = b % 48, h = rem >> 2, it = rem & 3;
    int wave = threadIdx.x >> 6, lane = threadIdx.x & 63;
    int quad = lane >> 4, col = lane & 15;
    int i0 = it * 64 + wave * 16;

    const u16* qrow = qb + ((size_t)(i0 + col) * NB + n) * EMB + h * HD;
    bf16x8 a0 = __builtin_bit_cast(bf16x8, *(const uint4*)(qrow + quad * 8));
    bf16x8 a1 = __builtin_bit_cast(bf16x8, *(const uint4*)(qrow + 32 + quad * 8));

    f32x4 sc[16];
    #pragma unroll
    for (int t = 0; t < 16; ++t) {
        const u16* krow = kb + ((size_t)(t * 16 + col) * NB + n) * EMB + h * HD;
        bf16x8 b0 = __builtin_bit_cast(bf16x8, *(const uint4*)(krow + quad * 8));
        bf16x8 b1 = __builtin_bit_cast(bf16x8, *(const uint4*)(krow + 32 + quad * 8));
        f32x4 acc = (f32x4){0.f, 0.f, 0.f, 0.f};
        acc = __builtin_amdgcn_mfma_f32_16x16x32_bf16(a0, b0, acc, 0, 0, 0);
        acc = __builtin_amdgcn_mfma_f32_16x16x32_bf16(a1, b1, acc, 0, 0, 0);
        sc[t] = acc;
    }

    #pragma unroll
    for (int reg = 0; reg < 4; ++reg) {
        const float* Srow = S + (((size_t)n * NH + h) * L_SEQ + i0 + quad * 4 + reg) * L_SEQ + col;
        float m = -1e30f;
        #pragma unroll
        for (int t = 0; t < 16; ++t) {
            float v = sc[t][reg] + Srow[t * 16];
            sc[t][reg] = v;
            m = fmaxf(m, v);
        }
        #pragma unroll
        for (int off = 1; off < 16; off <<= 1) m = fmaxf(m, __shfl_xor(m, off));
        float sum = 0.f;
        #pragma unroll
        for (int t = 0; t < 16; ++t) {
            float e = __expf(sc[t][reg] - m);
            sc[t][reg] = e;
            sum += e;
        }
        #pragma unroll
        for (int off = 1; off < 16; off <<= 1) sum += __shfl_xor(sum, off);
        float inv = 1.0f / sum;
        #pragma unroll
        for (int t = 0; t < 16; ++t)
            p_lds[wave][quad * 4 + reg][t * 16 + col] = f2b(sc[t][reg] * inv);
    }

    bf16x8 ap[8];
    #pragma unroll
    for (int kt = 0; kt < 8; ++kt)
        ap[kt] = __builtin_bit_cast(bf16x8, *(const uint4*)&p_lds[wave][col][kt * 32 + quad * 8]);
    #pragma unroll
    for (int nt = 0; nt < 4; ++nt) {
        const u16* vrow = vt + ((size_t)n * EMB + h * HD + nt * 16 + col) * L_SEQ;
        f32x4 acc = (f32x4){0.f, 0.f, 0.f, 0.f};
        #pragma unroll
        for (int kt = 0; kt < 8; ++kt) {
            bf16x8 bp = __builtin_bit_cast(bf16x8, *(const uint4*)(vrow + kt * 32 + quad * 8));
            acc = __builtin_amdgcn_mfma_f32_16x16x32_bf16(ap[kt], bp, acc, 0, 0, 0);
        }
        #pragma unroll
        for (int reg = 0; reg < 4; ++reg) {
            int ii = i0 + quad * 4 + reg;
            ctxb[((size_t)ii * NB + n) * EMB + h * HD + nt * 16 + col] = f2b(acc[reg]);
        }
    }
}

// ln1: y = p0 + p1 + src + out_bias; LN -> x1b (bf16); y2 = LN_out + lin2_bias.
__global__ void ln1_kernel(const float* __restrict__ p0, const float* __restrict__ p1,
                           const void* __restrict__ src, const float* __restrict__ biasf,
                           const void* __restrict__ g, const void* __restrict__ b,
                           u16* __restrict__ x1b, float* __restrict__ y2,
                           const int* __restrict__ flagp) {
    const int f32 = *flagp;
    int r = blockIdx.x;
    int t = threadIdx.x;
    __shared__ float red[256];
    float x[3];
    #pragma unroll
    for (int p = 0; p < 3; ++p) {
        int e = t + p * 256;
        size_t oi = (size_t)r * EMB + e;
        x[p] = p0[oi] + p1[oi] + ldE(src, oi, f32) + biasf[2304 + e];
    }
    red[t] = x[0] + x[1] + x[2];
    __syncthreads();
    for (int off = 128; off; off >>= 1) {
        if (t < off) red[t] += red[t + off];
        __syncthreads();
    }
    float mean = red[0] * (1.0f / EMB);
    __syncthreads();
    float d0 = x[0] - mean, d1 = x[1] - mean, d2 = x[2] - mean;
    red[t] = d0 * d0 + d1 * d1 + d2 * d2;
    __syncthreads();
    for (int off = 128; off; off >>= 1) {
        if (t < off) red[t] += red[t + off];
        __syncthreads();
    }
    float rstd = rsqrtf(red[0] * (1.0f / EMB) + 1e-5f);
    float vs[3] = {d0, d1, d2};
    #pragma unroll
    for (int p = 0; p < 3; ++p) {
        int e = t + p * 256;
        float v = vs[p] * rstd * ldE(g, e, f32) + ldE(b, e, f32);
        size_t oi = (size_t)r * EMB + e;
        x1b[oi] = f2b(v);
        y2[oi] = v + biasf[6144 + e];
    }
}

// ln2 (final): LN(y2) -> d_out runtime dtype.
__global__ void ln2_kernel(const float* __restrict__ X, const void* __restrict__ g,
                           const void* __restrict__ b, void* __restrict__ outAny,
                           const int* __restrict__ flagp) {
    const int f32 = *flagp;
    int r = blockIdx.x;
    int t = threadIdx.x;
    __shared__ float red[256];
    float x0 = X[(size_t)r * EMB + t];
    float x1 = X[(size_t)r * EMB + t + 256];
    float x2 = X[(size_t)r * EMB + t + 512];
    red[t] = x0 + x1 + x2;
    __syncthreads();
    for (int off = 128; off; off >>= 1) {
        if (t < off) red[t] += red[t + off];
        __syncthreads();
    }
    float mean = red[0] * (1.0f / EMB);
    __syncthreads();
    float d0 = x0 - mean, d1 = x1 - mean, d2 = x2 - mean;
    red[t] = d0 * d0 + d1 * d1 + d2 * d2;
    __syncthreads();
    for (int off = 128; off; off >>= 1) {
        if (t < off) red[t] += red[t + off];
        __syncthreads();
    }
    float rstd = rsqrtf(red[0] * (1.0f / EMB) + 1e-5f);
    float vs[3] = {d0, d1, d2};
    #pragma unroll
    for (int p = 0; p < 3; ++p) {
        int e = t + p * 256;
        float v = vs[p] * rstd * ldE(g, e, f32) + ldE(b, e, f32);
        size_t oi = (size_t)r * EMB + e;
        if (f32) ((float*)outAny)[oi] = v;
        else     ((bf16*)outAny)[oi] = __float2bfloat16(v);
    }
}

extern "C" void kernel_launch(void* const* d_in, const int* in_sizes, int n_in,
                              void* d_out, int out_size, void* d_ws, size_t ws_size,
                              hipStream_t stream) {
    const void* src    = d_in[0];
    const void* pos    = d_in[1];
    const void* q_w    = d_in[2];
    const void* q_b    = d_in[3];
    const void* k_w    = d_in[4];
    const void* k_b    = d_in[5];
    const void* v_w    = d_in[6];
    const void* v_b    = d_in[7];
    const void* p_w    = d_in[8];
    const void* p_b    = d_in[9];
    const void* out_w  = d_in[10];
    const void* out_b  = d_in[11];
    const void* lin1_w = d_in[12];
    const void* lin1_b = d_in[13];
    const void* lin2_w = d_in[14];
    const void* lin2_b = d_in[15];
    const void* n1_g   = d_in[16];
    const void* n1_b   = d_in[17];
    const void* n2_g   = d_in[18];
    const void* n2_b   = d_in[19];

    float* f = (float*)d_ws;
    int*   flagp = (int*)f;                              // 16
    float* biasf = f + 16;                               // 6912
    u16*   xb    = (u16*)(f + 6928);                     // 393216 f
    u16*   wqkv  = (u16*)(f + 400144);                   // 884736 f (dead after QKV gemm)
    u16*   owb   = (u16*)(f + 1284880);                  // 294912 f
    u16*   l1b   = (u16*)(f + 1579792);                  // 1179648 f
    u16*   l2b   = (u16*)(f + 2759440);                  // 1179648 f
    u16*   qbp   = (u16*)(f + 3939088);                  // 393216 f
    u16*   kbp   = (u16*)(f + 4332304);                  // 393216 f
    u16*   vtb   = (u16*)(f + 4725520);                  // 393216 f  vt[n][e][i]
    u16*   qp_b  = (u16*)(f + 5118736);                  // 524288 f
    float* qpb   = f + 5643024;                          // 12288
    float* S     = f + 5655312;                          // 3145728 (ends 8801040)
    u16*   ctxb  = (u16*)(f + 8801040);                  // 393216 f (ends 9194256)
    // overlays (regions dead at time of use):
    u16*   ffb   = (u16*)S;                              // S[0 : 1572864]
    float* y2    = S + 1572864;                          // S[1572864 : 2359296]
    float* pOut1 = S + 2359296;                          // S[2359296 : 3145728]
    float* pOut0 = f + 400144;                           // wqkv region (dead)
    u16*   x1b   = vtb;                                  // vt dead after attn3

    detect_kernel<<<1, 256, 0, stream>>>(src, flagp);

    pack_all<<<3867, 256, 0, stream>>>(xb, wqkv, owb, l1b, l2b, biasf,
                                       src, q_w, k_w, v_w, out_w, lin1_w, lin2_w,
                                       q_b, k_b, v_b, out_b, lin1_b, lin2_b, flagp);

    // QKV fused GEMM (N=2304); V written transposed
    mfma_gemm<0><<<dim3(18, 8), 256, 0, stream>>>(
        xb, wqkv, biasf, qbp, kbp, vtb, nullptr, nullptr, EMB, EMB, 0);

    // position scores
    qp_kernel<<<NB * NH * L_SEQ, 64, 0, stream>>>(qbp, p_w, p_b, qp_b, qpb, flagp);
    s2_mfma<<<NB * L_SEQ / 4, 256, 0, stream>>>(qp_b, qpb, pos, S, flagp);

    // MFMA attention
    attn3_kernel<<<NB * NH * 4, 256, 0, stream>>>(qbp, kbp, vtb, S, ctxb);

    // out projection, split-K=2 -> partials pOut0/pOut1 (bias+residual in ln1)
    mfma_gemm<4><<<dim3(6, 8, 2), 256, 0, stream>>>(
        ctxb, owb, nullptr, nullptr, nullptr, nullptr, pOut0, pOut1, 384, EMB, 384);

    // ln1: reduce partials + src + out_bias, LN -> x1b; y2 = LN + lin2_bias
    ln1_kernel<<<1024, 256, 0, stream>>>(pOut0, pOut1, src, biasf, n1_g, n1_b,
                                         x1b, y2, flagp);

    // lin1 + GELU -> ffb
    mfma_gemm<2><<<dim3(24, 8), 256, 0, stream>>>(
        x1b, l1b, biasf + 3072, ffb, nullptr, nullptr, nullptr, nullptr, EMB, EMB, 0);

    // lin2, split-K=4, atomic accumulate into y2 (pre-initialized by ln1)
    mfma_gemm<5><<<dim3(6, 8, 4), 256, 0, stream>>>(
        ffb, l2b, nullptr, nullptr, nullptr, nullptr, y2, nullptr, 768, DFF, 768);

    ln2_kernel<<<1024, 256, 0, stream>>>(y2, n2_g, n2_b, d_out, flagp);
}